// Round 10
// baseline (377.265 us; speedup 1.0000x reference)
//
#include <hip/hip_runtime.h>

#define N_ENT 100000
#define N_HE  20000
#define DD    128

// Global row space (concatenated over the 5 matrices)
#define RB_A   0
#define RB_P1  100000
#define RB_P2  120000
#define RB_L1  220000
#define RB_L2  240000
#define NROWS_TOT 340000

// Bucket geometry: regions {A,P1,P2,L1,L2}
#define NB 452
#define TILE 3072
#define EPT  12   // entries per thread = TILE/256

typedef float f32x4 __attribute__((ext_vector_type(4)));
typedef short bf16x8 __attribute__((ext_vector_type(8)));

__device__ __forceinline__ int bucket_region(int b) {
    return (b < 98) ? 0 : (b < 177) ? 1 : (b < 275) ? 2 : (b < 354) ? 3 : 4;
}
__device__ __forceinline__ int seg_shift(int s)      { return (s == 1 || s == 3) ? 8 : 10; }
__device__ __forceinline__ int seg_bucketbase(int s) { return s == 0 ? 0 : s == 1 ? 98 : s == 2 ? 177 : s == 3 ? 275 : 354; }
__device__ __forceinline__ int seg_cap(int s)        { return s == 0 ? 17408 : (s == 1 || s == 3) ? 13824 : 11264; }
__device__ __forceinline__ long long seg_arenabase(int s) {
    return s == 0 ? 0LL : s == 1 ? 1705984LL : s == 2 ? 2798080LL : s == 3 ? 3901952LL : 4994048LL;
}
__device__ __forceinline__ int seg_rowbase(int s)    { return s == 0 ? 0 : s == 1 ? 100000 : s == 2 ? 120000 : s == 3 ? 220000 : 240000; }
__device__ __forceinline__ int seg_rows(int s)       { return (s == 1 || s == 3) ? 20000 : 100000; }

__device__ __forceinline__ float bf_lo(unsigned u) { return __uint_as_float(u << 16); }
__device__ __forceinline__ float bf_hi(unsigned u) { return __uint_as_float(u & 0xffff0000u); }
__device__ __forceinline__ unsigned short f2bf(float f) {
    unsigned u = __float_as_uint(f);
    unsigned r = (u + 0x7fffu + ((u >> 16) & 1u)) >> 16;   // RNE
    return (unsigned short)r;
}
__device__ __forceinline__ unsigned pack_bf16(float a, float b) {
    return (unsigned)f2bf(a) | ((unsigned)f2bf(b) << 16);
}
__device__ __forceinline__ float lrelu(float x) { return x > 0.0f ? x : 0.01f * x; }
__device__ __forceinline__ float i8f(unsigned u, int b) {
    return (float)((int)(u << (24 - 8 * b)) >> 24);
}

// ---------------- ego fp32 -> block-scaled int8 (one 32-lane half-wave per row) ----------------
__global__ __launch_bounds__(256) void quant_ego_kernel(
    const float* __restrict__ ego, unsigned* __restrict__ ego_q,
    float* __restrict__ ego_scale)
{
    int row = (blockIdx.x * 256 + threadIdx.x) >> 5;
    if (row >= N_ENT) return;
    int l = threadIdx.x & 31;
    const float4 v = *(const float4*)(ego + (long long)row * DD + l * 4);
    float m = fmaxf(fmaxf(fabsf(v.x), fabsf(v.y)), fmaxf(fabsf(v.z), fabsf(v.w)));
    for (int d = 1; d < 32; d <<= 1) m = fmaxf(m, __shfl_xor(m, d, 32));
    float inv = (m > 0.0f) ? 127.0f / m : 0.0f;
    int q0 = __float2int_rn(v.x * inv);
    int q1 = __float2int_rn(v.y * inv);
    int q2 = __float2int_rn(v.z * inv);
    int q3 = __float2int_rn(v.w * inv);
    unsigned pk = (q0 & 255) | ((q1 & 255) << 8) | ((q2 & 255) << 16) | ((q3 & 255) << 24);
    ego_q[row * 32 + l] = pk;
    if (l == 0) ego_scale[row] = m * (1.0f / 127.0f);
}

struct BuildArgs {
    const int*   rows[5];
    const int*   cols[5];
    const float* vals[5];
    int nnzbase[6];
};

__device__ __forceinline__ void seg_of(int i, const int* nnzbase, int& seg, int& li) {
    int s = 0;
    s += (i >= nnzbase[1]);
    s += (i >= nnzbase[2]);
    s += (i >= nnzbase[3]);
    s += (i >= nnzbase[4]);
    seg = s; li = i - nnzbase[s];
}

// ---------------- Phase A: LDS-binned partition into bucket arena ----------------
__global__ __launch_bounds__(256, 4) void partition_kernel(
    BuildArgs a, int* __restrict__ gcursor, int2* __restrict__ arena)
{
    __shared__ int2 staging[TILE];              // 24 KB
    __shared__ unsigned short posb[TILE];       // 6 KB
    __shared__ int  hist[NB];
    __shared__ int  excl[NB + 1];
    __shared__ int  cursor[NB];
    __shared__ int  gofs[NB];                   // gbase[b] - excl[b]

    const int t = threadIdx.x;
    const int tile_base = blockIdx.x * TILE;
    const int total = a.nnzbase[5];
    int tile_n = total - tile_base;
    if (tile_n > TILE) tile_n = TILE;
    if (tile_n <= 0) return;

    for (int i = t; i < NB; i += 256) hist[i] = 0;
    __syncthreads();

    int pk[EPT];
#pragma unroll
    for (int q = 0; q < EPT; ++q) {
        int j = t + q * 256;
        pk[q] = -1;
        if (j < tile_n) {
            int i = tile_base + j;
            int seg, li; seg_of(i, a.nnzbase, seg, li);
            int row = a.rows[seg][li];
            int sh = seg_shift(seg);
            int b = seg_bucketbase(seg) + (row >> sh);
            int rl = row & ((1 << sh) - 1);
            pk[q] = (b << 10) | rl;
            atomicAdd(&hist[b], 1);
        }
    }
    __syncthreads();

    if (t < 64) {
        int carry = 0;
        for (int base = 0; base < NB; base += 64) {
            int idx = base + t;
            int v = (idx < NB) ? hist[idx] : 0;
            int inc = v;
            for (int d = 1; d < 64; d <<= 1) {
                int u = __shfl_up(inc, d, 64);
                if (t >= d) inc += u;
            }
            if (idx < NB) excl[idx] = carry + inc - v;
            carry += __shfl(inc, 63, 64);
        }
        if (t == 0) excl[NB] = carry;
    }
    __syncthreads();

    for (int b = t; b < NB; b += 256) {
        int c = hist[b];
        int e = excl[b];
        int gb = (c > 0) ? atomicAdd(&gcursor[b], c) : 0;
        cursor[b] = e;
        gofs[b] = gb - e;
    }
    __syncthreads();

#pragma unroll
    for (int q = 0; q < EPT; ++q) {
        int j = t + q * 256;
        if (j < tile_n) {
            int i = tile_base + j;
            int seg, li; seg_of(i, a.nnzbase, seg, li);
            int col = a.cols[seg][li];
            float v = a.vals[seg][li];
            int b = pk[q] >> 10;
            int rl = pk[q] & 1023;
            int pos = atomicAdd(&cursor[b], 1);
            staging[pos] = make_int2((rl << 17) | col, __float_as_int(v));
        }
    }
    __syncthreads();

    for (int b = t; b < NB; b += 256) {
        int lo = excl[b], hi = excl[b + 1];
        for (int p = lo; p < hi; ++p) posb[p] = (unsigned short)b;
    }
    __syncthreads();

    for (int p = t; p < tile_n; p += 256) {
        int b = posb[p];
        int reg = bucket_region(b);
        long long slot = seg_arenabase(reg) + (long long)(b - seg_bucketbase(reg)) * seg_cap(reg);
        arena[slot + gofs[b] + p] = staging[p];
    }
}

// ---------------- bucket-count exclusive scan ----------------
__global__ __launch_bounds__(512) void bucket_scan_kernel(
    const int* __restrict__ gcursor, int* __restrict__ bbase, int* __restrict__ rp)
{
    __shared__ int tmp[512];
    int t = threadIdx.x;
    int v = (t < NB) ? gcursor[t] : 0;
    tmp[t] = v;
    __syncthreads();
    for (int d = 1; d < 512; d <<= 1) {
        int u = (t >= d) ? tmp[t - d] : 0;
        __syncthreads();
        tmp[t] += u;
        __syncthreads();
    }
    if (t < NB) bbase[t] = tmp[t] - v;
    if (t == NB - 1) rp[NROWS_TOT] = tmp[t];
}

// ---------------- Phase B: per-bucket counting sort -> final cv + rp ----------------
// Regions A/P1/L1 gather from ego: fold ego_scale[col] into the value here.
__global__ __launch_bounds__(256) void bucket_sort_kernel(
    const int* __restrict__ gcursor, const int* __restrict__ bbase,
    const int2* __restrict__ arena, const float* __restrict__ ego_scale,
    int2* __restrict__ cv, int* __restrict__ rp)
{
    __shared__ int hist[1024];
    __shared__ int excl[1024];
    __shared__ int wsum[4];

    const int b = blockIdx.x;
    const int t = threadIdx.x;
    const int reg = bucket_region(b);
    const int sh = seg_shift(reg);
    const int stride = 1 << sh;
    const int lb = b - seg_bucketbase(reg);
    const int row_base_local = lb << sh;
    int nrows = seg_rows(reg) - row_base_local;
    if (nrows > stride) nrows = stride;
    const long long slot = seg_arenabase(reg) + (long long)lb * seg_cap(reg);
    const int count = gcursor[b];
    const int fbase = bbase[b];
    const bool fold = (reg == 0) || (reg == 1) || (reg == 3);

    for (int i = t; i < 1024; i += 256) hist[i] = 0;
    __syncthreads();

    for (int j = t; j < count; j += 256) {
        int key = arena[slot + j].x;
        atomicAdd(&hist[key >> 17], 1);
    }
    __syncthreads();

    {
        const int lane = t & 63, wave = t >> 6;
        int v[4]; int s = 0;
#pragma unroll
        for (int q = 0; q < 4; ++q) { v[q] = hist[t * 4 + q]; s += v[q]; }
        int inc = s;
        for (int d = 1; d < 64; d <<= 1) {
            int u = __shfl_up(inc, d, 64);
            if (lane >= d) inc += u;
        }
        if (lane == 63) wsum[wave] = inc;
        __syncthreads();
        int woff = 0;
        for (int w = 0; w < wave; ++w) woff += wsum[w];
        int run = woff + inc - s;
#pragma unroll
        for (int q = 0; q < 4; ++q) { excl[t * 4 + q] = run; run += v[q]; }
    }
    __syncthreads();

    const int grow0 = seg_rowbase(reg) + row_base_local;
    for (int r = t; r < nrows; r += 256)
        rp[grow0 + r] = fbase + excl[r];
    __syncthreads();

    for (int j = t; j < count; j += 256) {
        int2 e = arena[slot + j];
        int r = e.x >> 17;
        int c = e.x & 0x1FFFF;
        float v = __int_as_float(e.y);
        if (fold) v *= ego_scale[c];
        int pos = atomicAdd(&excl[r], 1);
        cv[fbase + pos] = make_int2(c, __float_as_int(v));
    }
}

// ---------------- SpMM gather walks (group-of-4 scheme, int8 x) ----------------
// Row = 128 B (one cache line). Lane covers dims (lane&15)*8..+7 via uint2.
__device__ __forceinline__ void walk_row_i8(
    const int2* __restrict__ cv, int start, int end, int lane,
    const unsigned* __restrict__ xq, float* acc)
{
    const int g  = lane >> 4;
    const int p8 = (lane & 15) * 2;

    for (int sb = start; sb < end; sb += 64) {
        int nn = end - sb; if (nn > 64) nn = 64;
        int2 mycv = make_int2(0, 0);
        if (lane < nn) mycv = cv[sb + lane];
        const int nn1 = nn - 1;
#pragma unroll 2
        for (int jb = 0; jb < nn; jb += 4) {
            int idx  = jb + g;
            int idxc = idx < nn1 ? idx : nn1;
            int   cs = __shfl(mycv.x, idxc, 64);
            float vs = __shfl(__int_as_float(mycv.y), idxc, 64);
            vs = (idx <= nn1) ? vs : 0.0f;
            const uint2 u = *reinterpret_cast<const uint2*>(xq + cs * 32 + p8);
            acc[0] = fmaf(vs, i8f(u.x, 0), acc[0]);
            acc[1] = fmaf(vs, i8f(u.x, 1), acc[1]);
            acc[2] = fmaf(vs, i8f(u.x, 2), acc[2]);
            acc[3] = fmaf(vs, i8f(u.x, 3), acc[3]);
            acc[4] = fmaf(vs, i8f(u.y, 0), acc[4]);
            acc[5] = fmaf(vs, i8f(u.y, 1), acc[5]);
            acc[6] = fmaf(vs, i8f(u.y, 2), acc[6]);
            acc[7] = fmaf(vs, i8f(u.y, 3), acc[7]);
        }
    }
}

// Same, but with a per-x-row dequant scale folded into the value at cv-load time
// (scale table is small: 80 KB, L2/L1-resident).
__device__ __forceinline__ void walk_row_i8s(
    const int2* __restrict__ cv, int start, int end, int lane,
    const unsigned* __restrict__ xq, const float* __restrict__ xs, float* acc)
{
    const int g  = lane >> 4;
    const int p8 = (lane & 15) * 2;

    for (int sb = start; sb < end; sb += 64) {
        int nn = end - sb; if (nn > 64) nn = 64;
        int2 mycv = make_int2(0, 0);
        if (lane < nn) {
            mycv = cv[sb + lane];
            float v = __int_as_float(mycv.y) * xs[mycv.x];
            mycv.y = __float_as_int(v);
        }
        const int nn1 = nn - 1;
#pragma unroll 2
        for (int jb = 0; jb < nn; jb += 4) {
            int idx  = jb + g;
            int idxc = idx < nn1 ? idx : nn1;
            int   cs = __shfl(mycv.x, idxc, 64);
            float vs = __shfl(__int_as_float(mycv.y), idxc, 64);
            vs = (idx <= nn1) ? vs : 0.0f;
            const uint2 u = *reinterpret_cast<const uint2*>(xq + cs * 32 + p8);
            acc[0] = fmaf(vs, i8f(u.x, 0), acc[0]);
            acc[1] = fmaf(vs, i8f(u.x, 1), acc[1]);
            acc[2] = fmaf(vs, i8f(u.x, 2), acc[2]);
            acc[3] = fmaf(vs, i8f(u.x, 3), acc[3]);
            acc[4] = fmaf(vs, i8f(u.y, 0), acc[4]);
            acc[5] = fmaf(vs, i8f(u.y, 1), acc[5]);
            acc[6] = fmaf(vs, i8f(u.y, 2), acc[6]);
            acc[7] = fmaf(vs, i8f(u.y, 3), acc[7]);
        }
    }
}

__device__ __forceinline__ void reduce_groups(float* acc)
{
#pragma unroll
    for (int e = 0; e < 8; ++e) {
        acc[e] += __shfl_xor(acc[e], 16, 64);
        acc[e] += __shfl_xor(acc[e], 32, 64);
    }
}

// stage 1: h1 = p1 @ ego, h2 = l1 @ ego  (int8 gather, int8 block-scaled outputs)
__global__ __launch_bounds__(256) void spmm_stage1_kernel(
    const int* __restrict__ rp, const int2* __restrict__ cv,
    const unsigned* __restrict__ ego_q,
    unsigned* __restrict__ h1q, float* __restrict__ h1s,
    unsigned* __restrict__ h2q, float* __restrict__ h2s)
{
    int wid = (blockIdx.x * 256 + threadIdx.x) >> 6;
    int lane = threadIdx.x & 63;
    if (wid >= 2 * N_HE) return;
    int rbase; unsigned* yq; float* ys; int lrow;
    if (wid < N_HE) { rbase = RB_P1 + wid;          yq = h1q; ys = h1s; lrow = wid; }
    else            { rbase = RB_L1 + (wid - N_HE); yq = h2q; ys = h2s; lrow = wid - N_HE; }

    float acc[8] = {0, 0, 0, 0, 0, 0, 0, 0};
    walk_row_i8(cv, rp[rbase], rp[rbase + 1], lane, ego_q, acc);
    reduce_groups(acc);

    // row absmax across the 16 dim-slots (lanes mirror in groups of 16)
    float m = 0.0f;
#pragma unroll
    for (int e = 0; e < 8; ++e) m = fmaxf(m, fabsf(acc[e]));
    for (int d = 1; d < 16; d <<= 1) m = fmaxf(m, __shfl_xor(m, d, 64));
    float inv = (m > 0.0f) ? 127.0f / m : 0.0f;

    if (lane < 16) {
        int q0 = __float2int_rn(acc[0] * inv), q1 = __float2int_rn(acc[1] * inv);
        int q2 = __float2int_rn(acc[2] * inv), q3 = __float2int_rn(acc[3] * inv);
        int q4 = __float2int_rn(acc[4] * inv), q5 = __float2int_rn(acc[5] * inv);
        int q6 = __float2int_rn(acc[6] * inv), q7 = __float2int_rn(acc[7] * inv);
        uint2 o;
        o.x = (q0 & 255) | ((q1 & 255) << 8) | ((q2 & 255) << 16) | ((q3 & 255) << 24);
        o.y = (q4 & 255) | ((q5 & 255) << 8) | ((q6 & 255) << 16) | ((q7 & 255) << 24);
        *reinterpret_cast<uint2*>(yq + lrow * 32 + lane * 2) = o;
        if (lane == 0) ys[lrow] = m * (1.0f / 127.0f);
    }
}

// stage 2: side = A@ego (int8) + p2@h1 + l2@h2 (int8 + scale fold)  (output fp32)
__global__ __launch_bounds__(256) void spmm_stage2_kernel(
    const int* __restrict__ rp, const int2* __restrict__ cv,
    const unsigned* __restrict__ ego_q,
    const unsigned* __restrict__ h1q, const float* __restrict__ h1s,
    const unsigned* __restrict__ h2q, const float* __restrict__ h2s,
    float* __restrict__ side)
{
    int wid = (blockIdx.x * 256 + threadIdx.x) >> 6;
    int lane = threadIdx.x & 63;
    if (wid >= N_ENT) return;

    float acc[8] = {0, 0, 0, 0, 0, 0, 0, 0};
    walk_row_i8 (cv, rp[RB_A  + wid], rp[RB_A  + wid + 1], lane, ego_q, acc);
    walk_row_i8s(cv, rp[RB_P2 + wid], rp[RB_P2 + wid + 1], lane, h1q, h1s, acc);
    walk_row_i8s(cv, rp[RB_L2 + wid], rp[RB_L2 + wid + 1], lane, h2q, h2s, acc);
    reduce_groups(acc);

    if (lane < 16) {
        float* yp = side + (long long)wid * DD + (lane & 15) * 8;
        float4 a0 = make_float4(acc[0], acc[1], acc[2], acc[3]);
        float4 a1 = make_float4(acc[4], acc[5], acc[6], acc[7]);
        *reinterpret_cast<float4*>(yp)     = a0;
        *reinterpret_cast<float4*>(yp + 4) = a1;
    }
}

// ---------------- MFMA dense epilogue (512 threads, 16 rows/wave) ----------------
union BfFrag { unsigned u[4]; bf16x8 v; };

__global__ __launch_bounds__(512, 4) void dense_mfma_kernel(
    const float* __restrict__ ego, const float* __restrict__ side,
    const float* __restrict__ W1, const float* __restrict__ b1,
    const float* __restrict__ W2, const float* __restrict__ b2,
    float* __restrict__ out)
{
    __shared__ unsigned Wb1[8192];   // 32 KB: W1 bf16, swizzled
    __shared__ unsigned Wb2[8192];   // 32 KB: W2 bf16, swizzled

    const int tid = threadIdx.x;

    for (int idx = tid; idx < 8192; idx += 512) {
        int row = idx >> 6, pc = idx & 63;
        unsigned pk1 = pack_bf16(W1[row * 128 + pc * 2], W1[row * 128 + pc * 2 + 1]);
        unsigned pk2 = pack_bf16(W2[row * 128 + pc * 2], W2[row * 128 + pc * 2 + 1]);
        int boff = row * 256 + ((pc * 4) ^ ((row & 7) << 4));
        *(unsigned*)((char*)Wb1 + boff) = pk1;
        *(unsigned*)((char*)Wb2 + boff) = pk2;
    }
    __syncthreads();

    const int wave = tid >> 6;   // 0..7
    const int lane = tid & 63;
    const int m    = lane & 15;
    const int kg   = lane >> 4;

    float bs[8], bb[8];
#pragma unroll
    for (int c = 0; c < 8; ++c) {
        bs[c] = b1[c * 16 + m];
        bb[c] = b2[c * 16 + m];
    }

    for (int wt = blockIdx.x * 8 + wave; wt < 6250; wt += gridDim.x * 8) {
        const long long r0 = (long long)(wt * 16 + m) * DD;

        f32x4 accS[8], accB[8];
#pragma unroll
        for (int c = 0; c < 8; ++c) { accS[c] = (f32x4)0.0f; accB[c] = (f32x4)0.0f; }

#pragma unroll 1
        for (int kk = 0; kk < 4; ++kk) {
            const int kb = kk * 32 + kg * 8;

            float4 ea = *(const float4*)(ego  + r0 + kb);
            float4 eb = *(const float4*)(ego  + r0 + kb + 4);
            float4 sa = *(const float4*)(side + r0 + kb);
            float4 sb = *(const float4*)(side + r0 + kb + 4);

            BfFrag aS, aB;
            aS.u[0] = pack_bf16(ea.x + sa.x, ea.y + sa.y);
            aS.u[1] = pack_bf16(ea.z + sa.z, ea.w + sa.w);
            aS.u[2] = pack_bf16(eb.x + sb.x, eb.y + sb.y);
            aS.u[3] = pack_bf16(eb.z + sb.z, eb.w + sb.w);
            aB.u[0] = pack_bf16(ea.x * sa.x, ea.y * sa.y);
            aB.u[1] = pack_bf16(ea.z * sa.z, ea.w * sa.w);
            aB.u[2] = pack_bf16(eb.x * sb.x, eb.y * sb.y);
            aB.u[3] = pack_bf16(eb.z * sb.z, eb.w * sb.w);

#pragma unroll
            for (int c = 0; c < 8; ++c) {
                int wrow = c * 16 + m;
                int boff = wrow * 256 + ((kk * 64 + (kg << 4)) ^ ((wrow & 7) << 4));
                bf16x8 w1 = *(const bf16x8*)((const char*)Wb1 + boff);
                bf16x8 w2 = *(const bf16x8*)((const char*)Wb2 + boff);
                accS[c] = __builtin_amdgcn_mfma_f32_16x16x32_bf16(aS.v, w1, accS[c], 0, 0, 0);
                accB[c] = __builtin_amdgcn_mfma_f32_16x16x32_bf16(aB.v, w2, accB[c], 0, 0, 0);
            }
        }

        // D mapping: col = lane&15 (=m), row = kg*4 + q
#pragma unroll
        for (int c = 0; c < 8; ++c) {
#pragma unroll
            for (int q = 0; q < 4; ++q) {
                int orow = wt * 16 + kg * 4 + q;
                out[(long long)orow * DD + c * 16 + m] =
                    lrelu(accS[c][q] + bs[c]) + lrelu(accB[c][q] + bb[c]);
            }
        }
    }
}

extern "C" void kernel_launch(void* const* d_in, const int* in_sizes, int n_in,
                              void* d_out, int out_size, void* d_ws, size_t ws_size,
                              hipStream_t stream)
{
    const float* ego = (const float*)d_in[0];
    const float* W1  = (const float*)d_in[16];
    const float* b1  = (const float*)d_in[17];
    const float* W2  = (const float*)d_in[18];
    const float* b2  = (const float*)d_in[19];

    BuildArgs a;
    a.rows[0] = (const int*)d_in[1];  a.cols[0] = (const int*)d_in[2];  a.vals[0] = (const float*)d_in[3];
    a.rows[1] = (const int*)d_in[4];  a.cols[1] = (const int*)d_in[5];  a.vals[1] = (const float*)d_in[6];
    a.rows[2] = (const int*)d_in[7];  a.cols[2] = (const int*)d_in[8];  a.vals[2] = (const float*)d_in[9];
    a.rows[3] = (const int*)d_in[10]; a.cols[3] = (const int*)d_in[11]; a.vals[3] = (const float*)d_in[12];
    a.rows[4] = (const int*)d_in[13]; a.cols[4] = (const int*)d_in[14]; a.vals[4] = (const float*)d_in[15];
    int nnz[5] = { in_sizes[1], in_sizes[4], in_sizes[7], in_sizes[10], in_sizes[13] };
    a.nnzbase[0] = 0;
    for (int s = 0; s < 5; ++s) a.nnzbase[s + 1] = a.nnzbase[s] + nnz[s];
    const int total = a.nnzbase[5];

    // ---- workspace carve (arena time-shares the side region) ----
    char* p = (char*)d_ws;
    float*    side     = (float*)p;
    int2*     arena    = (int2*)p;        p += (size_t)N_ENT * DD * 4;       // 51.2 MB (arena needs 48.8)
    unsigned* ego_q    = (unsigned*)p;    p += (size_t)N_ENT * 32 * 4;       // 12.8 MB (int8 rows, 128 B)
    float*    ego_scale= (float*)p;       p += (size_t)100096 * 4;           // 400 KB
    unsigned* h1q      = (unsigned*)p;    p += (size_t)N_HE * 32 * 4;        // 2.56 MB (int8 rows)
    unsigned* h2q      = (unsigned*)p;    p += (size_t)N_HE * 32 * 4;        // 2.56 MB
    float*    h1s      = (float*)p;       p += (size_t)20224 * 4;            // 80 KB
    float*    h2s      = (float*)p;       p += (size_t)20224 * 4;            // 80 KB
    int2*     cv       = (int2*)p;        p += (size_t)total * 8;            // 44.8 MB
    int*      rp       = (int*)p;         p += 340224 * 4;
    int*      gcursor  = (int*)p;         p += 512 * 4;
    int*      bbase    = (int*)p;         p += 512 * 4;

    // build
    hipMemsetAsync(gcursor, 0, NB * sizeof(int), stream);
    quant_ego_kernel<<<(N_ENT * 32 + 255) / 256, 256, 0, stream>>>(ego, ego_q, ego_scale);
    const int nblk_part = (total + TILE - 1) / TILE;
    partition_kernel<<<nblk_part, 256, 0, stream>>>(a, gcursor, arena);
    bucket_scan_kernel<<<1, 512, 0, stream>>>(gcursor, bbase, rp);
    bucket_sort_kernel<<<NB, 256, 0, stream>>>(gcursor, bbase, arena, ego_scale, cv, rp);

    // spmm (arena region is dead from here; side reuses it)
    spmm_stage1_kernel<<<(2 * N_HE) / 4, 256, 0, stream>>>(rp, cv, ego_q, h1q, h1s, h2q, h2s);
    spmm_stage2_kernel<<<N_ENT / 4, 256, 0, stream>>>(rp, cv, ego_q, h1q, h1s, h2q, h2s, side);

    // dense epilogue (MFMA, 512-thread blocks)
    dense_mfma_kernel<<<782, 512, 0, stream>>>(ego, side, W1, b1, W2, b2, (float*)d_out);
}

// Round 11
// 332.525 us; speedup vs baseline: 1.1345x; 1.1345x over previous
//
#include <hip/hip_runtime.h>

#define N_ENT 100000
#define N_HE  20000
#define DD    128

// Unified x-space rows: ego 0..100000, h1 100000..120000, h2 120000..140000
#define XROW_H1 100000
#define XROW_H2 120000
#define NXROWS  140000

// rp row spaces: S2 (A+P2+L2 merged) 0..100000 (+sentinel at 100000),
// P1 at 100001..120000 (+sentinel 120001), L1 at 120002..140001 (+sentinel 140002)
#define RP_S2  0
#define RP_P1  100001
#define RP_L1  120002
#define RP_LEN 140803

// Bucket geometry: region 0 = S2 (196 buckets, stride 512, cap 19968)
//                  region 1 = P1 (79 buckets, stride 256, cap 13824)
//                  region 2 = L1 (79 buckets, stride 256, cap 13824)
#define NB 354
#define TILE 3072
#define EPT  12   // entries per thread = TILE/256

typedef float f32x4 __attribute__((ext_vector_type(4)));
typedef short bf16x8 __attribute__((ext_vector_type(8)));

__device__ __forceinline__ int bucket_region(int b) {
    return (b < 196) ? 0 : (b < 275) ? 1 : 2;
}
__device__ __forceinline__ int reg_shift(int r)      { return r == 0 ? 9 : 8; }
__device__ __forceinline__ int reg_bucketbase(int r) { return r == 0 ? 0 : r == 1 ? 196 : 275; }
__device__ __forceinline__ int reg_cap(int r)        { return r == 0 ? 19968 : 13824; }
__device__ __forceinline__ long long reg_arenabase(int r) {
    return r == 0 ? 0LL : r == 1 ? 3913728LL : 5005824LL;
}
__device__ __forceinline__ int reg_rpbase(int r)     { return r == 0 ? RP_S2 : r == 1 ? RP_P1 : RP_L1; }
__device__ __forceinline__ int reg_rows(int r)       { return r == 0 ? 100000 : 20000; }

__device__ __forceinline__ unsigned short f2bf(float f) {
    unsigned u = __float_as_uint(f);
    unsigned r = (u + 0x7fffu + ((u >> 16) & 1u)) >> 16;   // RNE
    return (unsigned short)r;
}
__device__ __forceinline__ unsigned pack_bf16(float a, float b) {
    return (unsigned)f2bf(a) | ((unsigned)f2bf(b) << 16);
}
__device__ __forceinline__ float lrelu(float x) { return x > 0.0f ? x : 0.01f * x; }
__device__ __forceinline__ float i8f(unsigned u, int b) {
    return (float)((int)(u << (24 - 8 * b)) >> 24);
}

// ---------------- ego fp32 -> block-scaled int8 rows of xall ----------------
__global__ __launch_bounds__(256) void quant_ego_kernel(
    const float* __restrict__ ego, unsigned* __restrict__ xq,
    float* __restrict__ xs)
{
    int row = (blockIdx.x * 256 + threadIdx.x) >> 5;
    if (row >= N_ENT) return;
    int l = threadIdx.x & 31;
    const float4 v = *(const float4*)(ego + (long long)row * DD + l * 4);
    float m = fmaxf(fmaxf(fabsf(v.x), fabsf(v.y)), fmaxf(fabsf(v.z), fabsf(v.w)));
    for (int d = 1; d < 32; d <<= 1) m = fmaxf(m, __shfl_xor(m, d, 32));
    float inv = (m > 0.0f) ? 127.0f / m : 0.0f;
    int q0 = __float2int_rn(v.x * inv);
    int q1 = __float2int_rn(v.y * inv);
    int q2 = __float2int_rn(v.z * inv);
    int q3 = __float2int_rn(v.w * inv);
    unsigned pk = (q0 & 255) | ((q1 & 255) << 8) | ((q2 & 255) << 16) | ((q3 & 255) << 24);
    xq[row * 32 + l] = pk;
    if (l == 0) xs[row] = m * (1.0f / 127.0f);
}

struct BuildArgs {
    const int*   rows[5];
    const int*   cols[5];
    const float* vals[5];
    int nnzbase[6];
};

// seg -> bucket mapping: {A,P1,P2,L1,L2}
__device__ __forceinline__ int seg_bbase(int s)  { return (s == 1) ? 196 : (s == 3) ? 275 : 0; }
__device__ __forceinline__ int seg_shift2(int s) { return (s == 1 || s == 3) ? 8 : 9; }
__device__ __forceinline__ int seg_colofs(int s) { return (s == 2) ? XROW_H1 : (s == 4) ? XROW_H2 : 0; }

__device__ __forceinline__ void seg_of(int i, const int* nnzbase, int& seg, int& li) {
    int s = 0;
    s += (i >= nnzbase[1]);
    s += (i >= nnzbase[2]);
    s += (i >= nnzbase[3]);
    s += (i >= nnzbase[4]);
    seg = s; li = i - nnzbase[s];
}

// ---------------- Phase A: LDS-binned partition into bucket arena ----------------
__global__ __launch_bounds__(256, 4) void partition_kernel(
    BuildArgs a, int* __restrict__ gcursor, int2* __restrict__ arena)
{
    __shared__ int2 staging[TILE];              // 24 KB
    __shared__ unsigned short posb[TILE];       // 6 KB
    __shared__ int  hist[NB];
    __shared__ int  excl[NB + 1];
    __shared__ int  cursor[NB];
    __shared__ int  gofs[NB];                   // gbase[b] - excl[b]

    const int t = threadIdx.x;
    const int tile_base = blockIdx.x * TILE;
    const int total = a.nnzbase[5];
    int tile_n = total - tile_base;
    if (tile_n > TILE) tile_n = TILE;
    if (tile_n <= 0) return;

    for (int i = t; i < NB; i += 256) hist[i] = 0;
    __syncthreads();

    // pass 1: read rows once, histogram, cache (bucket<<9 | row_local) in regs
    int pk[EPT];
#pragma unroll
    for (int q = 0; q < EPT; ++q) {
        int j = t + q * 256;
        pk[q] = -1;
        if (j < tile_n) {
            int i = tile_base + j;
            int seg, li; seg_of(i, a.nnzbase, seg, li);
            int row = a.rows[seg][li];
            int sh = seg_shift2(seg);
            int b = seg_bbase(seg) + (row >> sh);
            int rl = row & ((1 << sh) - 1);
            pk[q] = (b << 9) | rl;
            atomicAdd(&hist[b], 1);
        }
    }
    __syncthreads();

    // wave 0: exclusive scan of hist -> excl
    if (t < 64) {
        int carry = 0;
        for (int base = 0; base < NB; base += 64) {
            int idx = base + t;
            int v = (idx < NB) ? hist[idx] : 0;
            int inc = v;
            for (int d = 1; d < 64; d <<= 1) {
                int u = __shfl_up(inc, d, 64);
                if (t >= d) inc += u;
            }
            if (idx < NB) excl[idx] = carry + inc - v;
            carry += __shfl(inc, 63, 64);
        }
        if (t == 0) excl[NB] = carry;
    }
    __syncthreads();

    for (int b = t; b < NB; b += 256) {
        int c = hist[b];
        int e = excl[b];
        int gb = (c > 0) ? atomicAdd(&gcursor[b], c) : 0;
        cursor[b] = e;
        gofs[b] = gb - e;
    }
    __syncthreads();

    // pass 2: read cols/vals, scatter into LDS staging grouped by bucket
#pragma unroll
    for (int q = 0; q < EPT; ++q) {
        int j = t + q * 256;
        if (j < tile_n) {
            int i = tile_base + j;
            int seg, li; seg_of(i, a.nnzbase, seg, li);
            int colp = a.cols[seg][li] + seg_colofs(seg);
            float v = a.vals[seg][li];
            int b = pk[q] >> 9;
            int rl = pk[q] & 511;
            int pos = atomicAdd(&cursor[b], 1);
            staging[pos] = make_int2((rl << 18) | colp, __float_as_int(v));
        }
    }
    __syncthreads();

    for (int b = t; b < NB; b += 256) {
        int lo = excl[b], hi = excl[b + 1];
        for (int p = lo; p < hi; ++p) posb[p] = (unsigned short)b;
    }
    __syncthreads();

    for (int p = t; p < tile_n; p += 256) {
        int b = posb[p];
        int reg = bucket_region(b);
        long long slot = reg_arenabase(reg) + (long long)(b - reg_bucketbase(reg)) * reg_cap(reg);
        arena[slot + gofs[b] + p] = staging[p];
    }
}

// ---------------- bucket-count exclusive scan (+rp sentinels) ----------------
__global__ __launch_bounds__(512) void bucket_scan_kernel(
    const int* __restrict__ gcursor, int* __restrict__ bbase, int* __restrict__ rp)
{
    __shared__ int tmp[512];
    int t = threadIdx.x;
    int v = (t < NB) ? gcursor[t] : 0;
    tmp[t] = v;
    __syncthreads();
    for (int d = 1; d < 512; d <<= 1) {
        int u = (t >= d) ? tmp[t - d] : 0;
        __syncthreads();
        tmp[t] += u;
        __syncthreads();
    }
    if (t < NB) bbase[t] = tmp[t] - v;
    // region sentinels
    if (t == 196) rp[RP_S2 + 100000] = tmp[t] - v;   // end of S2
    if (t == 275) rp[RP_P1 + 20000]  = tmp[t] - v;   // end of P1
    if (t == NB - 1) rp[RP_L1 + 20000] = tmp[t];     // total
}

// ---------------- Phase B: per-bucket counting sort -> final cv + rp ----------------
__global__ __launch_bounds__(256) void bucket_sort_kernel(
    const int* __restrict__ gcursor, const int* __restrict__ bbase,
    const int2* __restrict__ arena, int2* __restrict__ cv, int* __restrict__ rp)
{
    __shared__ int hist[512];
    __shared__ int excl[512];
    __shared__ int wsum[4];

    const int b = blockIdx.x;
    const int t = threadIdx.x;
    const int reg = bucket_region(b);
    const int sh = reg_shift(reg);
    const int stride = 1 << sh;
    const int lb = b - reg_bucketbase(reg);
    const int row_base_local = lb << sh;
    int nrows = reg_rows(reg) - row_base_local;
    if (nrows > stride) nrows = stride;
    const long long slot = reg_arenabase(reg) + (long long)lb * reg_cap(reg);
    const int count = gcursor[b];
    const int fbase = bbase[b];

    for (int i = t; i < 512; i += 256) hist[i] = 0;
    __syncthreads();

    for (int j = t; j < count; j += 256) {
        int key = arena[slot + j].x;
        atomicAdd(&hist[key >> 18], 1);
    }
    __syncthreads();

    // exclusive scan of 512 bins (2 per thread)
    {
        const int lane = t & 63, wave = t >> 6;
        int v0 = hist[t * 2], v1 = hist[t * 2 + 1];
        int s = v0 + v1;
        int inc = s;
        for (int d = 1; d < 64; d <<= 1) {
            int u = __shfl_up(inc, d, 64);
            if (lane >= d) inc += u;
        }
        if (lane == 63) wsum[wave] = inc;
        __syncthreads();
        int woff = 0;
        for (int w = 0; w < wave; ++w) woff += wsum[w];
        int run = woff + inc - s;
        excl[t * 2] = run;
        excl[t * 2 + 1] = run + v0;
    }
    __syncthreads();

    const int grow0 = reg_rpbase(reg) + row_base_local;
    for (int r = t; r < nrows; r += 256)
        rp[grow0 + r] = fbase + excl[r];
    __syncthreads();

    for (int j = t; j < count; j += 256) {
        int2 e = arena[slot + j];
        int r = e.x >> 18;
        int c = e.x & 0x3FFFF;
        int pos = atomicAdd(&excl[r], 1);
        cv[fbase + pos] = make_int2(c, e.y);
    }
}

// ---------------- SpMM gather walk: group-of-8, 16 B/lane, int8 x, scale fold ----------------
// Lane l: group g = l>>3 handles nnz jb+g; sublane s = l&7 loads 16 B of the row.
// acc[16] covers dims s*16 .. s*16+15. One wave-load = 8 nnz (8 lines, 1 KB).
__device__ __forceinline__ void walk_row8(
    const int2* __restrict__ cv, int start, int end, int lane,
    const unsigned* __restrict__ xq, const float* __restrict__ xs, float* acc)
{
    const int g = lane >> 3;
    const int s = lane & 7;

    for (int sb = start; sb < end; sb += 64) {
        int nn = end - sb; if (nn > 64) nn = 64;
        int2 mycv = make_int2(0, 0);
        float myv = 0.0f;
        if (lane < nn) {
            mycv = cv[sb + lane];
            myv = __int_as_float(mycv.y) * xs[mycv.x];
        }
        const int nn1 = nn - 1;
#pragma unroll 2
        for (int jb = 0; jb < nn; jb += 8) {
            int idx  = jb + g;
            int idxc = idx < nn1 ? idx : nn1;
            int   cs = __shfl(mycv.x, idxc, 64);
            float vs = __shfl(myv, idxc, 64);
            vs = (idx <= nn1) ? vs : 0.0f;
            const uint4 u = *reinterpret_cast<const uint4*>(xq + cs * 32 + s * 4);
#pragma unroll
            for (int w = 0; w < 4; ++w) {
                unsigned uw = (&u.x)[w];
                acc[w * 4 + 0] = fmaf(vs, i8f(uw, 0), acc[w * 4 + 0]);
                acc[w * 4 + 1] = fmaf(vs, i8f(uw, 1), acc[w * 4 + 1]);
                acc[w * 4 + 2] = fmaf(vs, i8f(uw, 2), acc[w * 4 + 2]);
                acc[w * 4 + 3] = fmaf(vs, i8f(uw, 3), acc[w * 4 + 3]);
            }
        }
    }
}

__device__ __forceinline__ void reduce_groups8(float* acc)
{
#pragma unroll
    for (int e = 0; e < 16; ++e) {
        acc[e] += __shfl_xor(acc[e], 8, 64);
        acc[e] += __shfl_xor(acc[e], 16, 64);
        acc[e] += __shfl_xor(acc[e], 32, 64);
    }
}

// stage 1: h1 = p1 @ ego, h2 = l1 @ ego  (int8 gather -> int8 block-scaled rows of xall)
__global__ __launch_bounds__(256) void spmm_stage1_kernel(
    const int* __restrict__ rp, const int2* __restrict__ cv,
    unsigned* __restrict__ xq, float* __restrict__ xs)
{
    int wid = (blockIdx.x * 256 + threadIdx.x) >> 6;
    int lane = threadIdx.x & 63;
    if (wid >= 2 * N_HE) return;
    int rbase, xrow;
    if (wid < N_HE) { rbase = RP_P1 + wid;           xrow = XROW_H1 + wid; }
    else            { rbase = RP_L1 + (wid - N_HE);  xrow = XROW_H2 + (wid - N_HE); }

    float acc[16];
#pragma unroll
    for (int e = 0; e < 16; ++e) acc[e] = 0.0f;
    walk_row8(cv, rp[rbase], rp[rbase + 1], lane, xq, xs, acc);
    reduce_groups8(acc);

    float m = 0.0f;
#pragma unroll
    for (int e = 0; e < 16; ++e) m = fmaxf(m, fabsf(acc[e]));
    m = fmaxf(m, __shfl_xor(m, 1, 64));
    m = fmaxf(m, __shfl_xor(m, 2, 64));
    m = fmaxf(m, __shfl_xor(m, 4, 64));
    float inv = (m > 0.0f) ? 127.0f / m : 0.0f;

    if (lane < 8) {
        uint4 o;
#pragma unroll
        for (int w = 0; w < 4; ++w) {
            int q0 = __float2int_rn(acc[w * 4 + 0] * inv);
            int q1 = __float2int_rn(acc[w * 4 + 1] * inv);
            int q2 = __float2int_rn(acc[w * 4 + 2] * inv);
            int q3 = __float2int_rn(acc[w * 4 + 3] * inv);
            (&o.x)[w] = (q0 & 255) | ((q1 & 255) << 8) | ((q2 & 255) << 16) | ((q3 & 255) << 24);
        }
        *reinterpret_cast<uint4*>(xq + xrow * 32 + lane * 4) = o;
        if (lane == 0) xs[xrow] = m * (1.0f / 127.0f);
    }
}

// stage 2: side = (A|p2|l2) @ xall  — ONE merged walk per output row
__global__ __launch_bounds__(256) void spmm_stage2_kernel(
    const int* __restrict__ rp, const int2* __restrict__ cv,
    const unsigned* __restrict__ xq, const float* __restrict__ xs,
    float* __restrict__ side)
{
    int wid = (blockIdx.x * 256 + threadIdx.x) >> 6;
    int lane = threadIdx.x & 63;
    if (wid >= N_ENT) return;

    float acc[16];
#pragma unroll
    for (int e = 0; e < 16; ++e) acc[e] = 0.0f;
    walk_row8(cv, rp[wid], rp[wid + 1], lane, xq, xs, acc);
    reduce_groups8(acc);

    if (lane < 8) {
        float* yp = side + (long long)wid * DD + lane * 16;
#pragma unroll
        for (int w = 0; w < 4; ++w)
            *reinterpret_cast<float4*>(yp + w * 4) =
                make_float4(acc[w * 4], acc[w * 4 + 1], acc[w * 4 + 2], acc[w * 4 + 3]);
    }
}

// ---------------- MFMA dense epilogue (512 threads, 16 rows/wave) ----------------
union BfFrag { unsigned u[4]; bf16x8 v; };

__global__ __launch_bounds__(512, 4) void dense_mfma_kernel(
    const float* __restrict__ ego, const float* __restrict__ side,
    const float* __restrict__ W1, const float* __restrict__ b1,
    const float* __restrict__ W2, const float* __restrict__ b2,
    float* __restrict__ out)
{
    __shared__ unsigned Wb1[8192];   // 32 KB: W1 bf16, swizzled
    __shared__ unsigned Wb2[8192];   // 32 KB: W2 bf16, swizzled

    const int tid = threadIdx.x;

    for (int idx = tid; idx < 8192; idx += 512) {
        int row = idx >> 6, pc = idx & 63;
        unsigned pk1 = pack_bf16(W1[row * 128 + pc * 2], W1[row * 128 + pc * 2 + 1]);
        unsigned pk2 = pack_bf16(W2[row * 128 + pc * 2], W2[row * 128 + pc * 2 + 1]);
        int boff = row * 256 + ((pc * 4) ^ ((row & 7) << 4));
        *(unsigned*)((char*)Wb1 + boff) = pk1;
        *(unsigned*)((char*)Wb2 + boff) = pk2;
    }
    __syncthreads();

    const int wave = tid >> 6;   // 0..7
    const int lane = tid & 63;
    const int m    = lane & 15;
    const int kg   = lane >> 4;

    float bs[8], bb[8];
#pragma unroll
    for (int c = 0; c < 8; ++c) {
        bs[c] = b1[c * 16 + m];
        bb[c] = b2[c * 16 + m];
    }

    for (int wt = blockIdx.x * 8 + wave; wt < 6250; wt += gridDim.x * 8) {
        const long long r0 = (long long)(wt * 16 + m) * DD;

        f32x4 accS[8], accB[8];
#pragma unroll
        for (int c = 0; c < 8; ++c) { accS[c] = (f32x4)0.0f; accB[c] = (f32x4)0.0f; }

#pragma unroll 1
        for (int kk = 0; kk < 4; ++kk) {
            const int kb = kk * 32 + kg * 8;

            float4 ea = *(const float4*)(ego  + r0 + kb);
            float4 eb = *(const float4*)(ego  + r0 + kb + 4);
            float4 sa = *(const float4*)(side + r0 + kb);
            float4 sb = *(const float4*)(side + r0 + kb + 4);

            BfFrag aS, aB;
            aS.u[0] = pack_bf16(ea.x + sa.x, ea.y + sa.y);
            aS.u[1] = pack_bf16(ea.z + sa.z, ea.w + sa.w);
            aS.u[2] = pack_bf16(eb.x + sb.x, eb.y + sb.y);
            aS.u[3] = pack_bf16(eb.z + sb.z, eb.w + sb.w);
            aB.u[0] = pack_bf16(ea.x * sa.x, ea.y * sa.y);
            aB.u[1] = pack_bf16(ea.z * sa.z, ea.w * sa.w);
            aB.u[2] = pack_bf16(eb.x * sb.x, eb.y * sb.y);
            aB.u[3] = pack_bf16(eb.z * sb.z, eb.w * sb.w);

#pragma unroll
            for (int c = 0; c < 8; ++c) {
                int wrow = c * 16 + m;
                int boff = wrow * 256 + ((kk * 64 + (kg << 4)) ^ ((wrow & 7) << 4));
                bf16x8 w1 = *(const bf16x8*)((const char*)Wb1 + boff);
                bf16x8 w2 = *(const bf16x8*)((const char*)Wb2 + boff);
                accS[c] = __builtin_amdgcn_mfma_f32_16x16x32_bf16(aS.v, w1, accS[c], 0, 0, 0);
                accB[c] = __builtin_amdgcn_mfma_f32_16x16x32_bf16(aB.v, w2, accB[c], 0, 0, 0);
            }
        }

        // D mapping: col = lane&15 (=m), row = kg*4 + q
#pragma unroll
        for (int c = 0; c < 8; ++c) {
#pragma unroll
            for (int q = 0; q < 4; ++q) {
                int orow = wt * 16 + kg * 4 + q;
                out[(long long)orow * DD + c * 16 + m] =
                    lrelu(accS[c][q] + bs[c]) + lrelu(accB[c][q] + bb[c]);
            }
        }
    }
}

extern "C" void kernel_launch(void* const* d_in, const int* in_sizes, int n_in,
                              void* d_out, int out_size, void* d_ws, size_t ws_size,
                              hipStream_t stream)
{
    const float* ego = (const float*)d_in[0];
    const float* W1  = (const float*)d_in[16];
    const float* b1  = (const float*)d_in[17];
    const float* W2  = (const float*)d_in[18];
    const float* b2  = (const float*)d_in[19];

    BuildArgs a;
    a.rows[0] = (const int*)d_in[1];  a.cols[0] = (const int*)d_in[2];  a.vals[0] = (const float*)d_in[3];
    a.rows[1] = (const int*)d_in[4];  a.cols[1] = (const int*)d_in[5];  a.vals[1] = (const float*)d_in[6];
    a.rows[2] = (const int*)d_in[7];  a.cols[2] = (const int*)d_in[8];  a.vals[2] = (const float*)d_in[9];
    a.rows[3] = (const int*)d_in[10]; a.cols[3] = (const int*)d_in[11]; a.vals[3] = (const float*)d_in[12];
    a.rows[4] = (const int*)d_in[13]; a.cols[4] = (const int*)d_in[14]; a.vals[4] = (const float*)d_in[15];
    int nnz[5] = { in_sizes[1], in_sizes[4], in_sizes[7], in_sizes[10], in_sizes[13] };
    a.nnzbase[0] = 0;
    for (int s = 0; s < 5; ++s) a.nnzbase[s + 1] = a.nnzbase[s] + nnz[s];
    const int total = a.nnzbase[5];

    // ---- workspace carve (arena time-shares the side region; arena = 48.8 MB) ----
    char* p = (char*)d_ws;
    float*    side    = (float*)p;
    int2*     arena   = (int2*)p;         p += (size_t)N_ENT * DD * 4;       // 51.2 MB
    unsigned* xq      = (unsigned*)p;     p += (size_t)140032 * 32 * 4;      // 17.9 MB (int8 rows x 140K)
    float*    xs      = (float*)p;        p += (size_t)140032 * 4;           // 560 KB
    int2*     cv      = (int2*)p;         p += (size_t)total * 8;            // 44.8 MB
    int*      rp      = (int*)p;          p += 141056 * 4;
    int*      gcursor = (int*)p;          p += 512 * 4;
    int*      bbase   = (int*)p;          p += 512 * 4;

    // build
    hipMemsetAsync(gcursor, 0, NB * sizeof(int), stream);
    quant_ego_kernel<<<(N_ENT * 32 + 255) / 256, 256, 0, stream>>>(ego, xq, xs);
    const int nblk_part = (total + TILE - 1) / TILE;
    partition_kernel<<<nblk_part, 256, 0, stream>>>(a, gcursor, arena);
    bucket_scan_kernel<<<1, 512, 0, stream>>>(gcursor, bbase, rp);
    bucket_sort_kernel<<<NB, 256, 0, stream>>>(gcursor, bbase, arena, cv, rp);

    // spmm (arena region is dead from here; side reuses it)
    spmm_stage1_kernel<<<(2 * N_HE) / 4, 256, 0, stream>>>(rp, cv, xq, xs);
    spmm_stage2_kernel<<<N_ENT / 4, 256, 0, stream>>>(rp, cv, xq, xs, side);

    // dense epilogue (MFMA, 512-thread blocks)
    dense_mfma_kernel<<<782, 512, 0, stream>>>(ego, side, W1, b1, W2, b2, (float*)d_out);
}

// Round 12
// 314.557 us; speedup vs baseline: 1.1994x; 1.0571x over previous
//
#include <hip/hip_runtime.h>

#define N_ENT 100000
#define N_HE  20000
#define DD    128

// Unified x-space rows: ego 0..100000, h1 100000..120000, h2 120000..140000
#define XROW_H1 100000
#define XROW_H2 120000

// rp row spaces
#define RP_S2  0
#define RP_P1  100001
#define RP_L1  120002

// Bucket geometry: ALL regions stride 256.
// region 0 = S2 (A+P2+L2 merged): 391 buckets, cap 10240
// region 1 = P1: 79 buckets, cap 13824 ; region 2 = L1: 79 buckets, cap 13824
#define NB 549
#define TILE 2048
#define EPT  8   // entries per thread = TILE/256

typedef float f32x4 __attribute__((ext_vector_type(4)));
typedef short bf16x8 __attribute__((ext_vector_type(8)));

__device__ __forceinline__ int bucket_region(int b) {
    return (b < 391) ? 0 : (b < 470) ? 1 : 2;
}
__device__ __forceinline__ int reg_bucketbase(int r) { return r == 0 ? 0 : r == 1 ? 391 : 470; }
__device__ __forceinline__ int reg_cap(int r)        { return r == 0 ? 10240 : 13824; }
__device__ __forceinline__ long long reg_arenabase(int r) {
    return r == 0 ? 0LL : r == 1 ? 4003840LL : 5095936LL;   // 391*10240 ; +79*13824
}
__device__ __forceinline__ int reg_rpbase(int r)     { return r == 0 ? RP_S2 : r == 1 ? RP_P1 : RP_L1; }
__device__ __forceinline__ int reg_rows(int r)       { return r == 0 ? 100000 : 20000; }

__device__ __forceinline__ unsigned short f2bf(float f) {
    unsigned u = __float_as_uint(f);
    unsigned r = (u + 0x7fffu + ((u >> 16) & 1u)) >> 16;   // RNE
    return (unsigned short)r;
}
__device__ __forceinline__ unsigned pack_bf16(float a, float b) {
    return (unsigned)f2bf(a) | ((unsigned)f2bf(b) << 16);
}
__device__ __forceinline__ float lrelu(float x) { return x > 0.0f ? x : 0.01f * x; }
__device__ __forceinline__ float i8f(unsigned u, int b) {
    return (float)((int)(u << (24 - 8 * b)) >> 24);
}

// ---------------- ego fp32 -> block-scaled int8 rows of xall ----------------
__global__ __launch_bounds__(256) void quant_ego_kernel(
    const float* __restrict__ ego, unsigned* __restrict__ xq,
    float* __restrict__ xs)
{
    int row = (blockIdx.x * 256 + threadIdx.x) >> 5;
    if (row >= N_ENT) return;
    int l = threadIdx.x & 31;
    const float4 v = *(const float4*)(ego + (long long)row * DD + l * 4);
    float m = fmaxf(fmaxf(fabsf(v.x), fabsf(v.y)), fmaxf(fabsf(v.z), fabsf(v.w)));
    for (int d = 1; d < 32; d <<= 1) m = fmaxf(m, __shfl_xor(m, d, 32));
    float inv = (m > 0.0f) ? 127.0f / m : 0.0f;
    int q0 = __float2int_rn(v.x * inv);
    int q1 = __float2int_rn(v.y * inv);
    int q2 = __float2int_rn(v.z * inv);
    int q3 = __float2int_rn(v.w * inv);
    unsigned pk = (q0 & 255) | ((q1 & 255) << 8) | ((q2 & 255) << 16) | ((q3 & 255) << 24);
    xq[row * 32 + l] = pk;
    if (l == 0) xs[row] = m * (1.0f / 127.0f);
}

struct BuildArgs {
    const int*   rows[5];
    const int*   cols[5];
    const float* vals[5];
    int nnzbase[6];
};

// seg -> bucket mapping: {A,P1,P2,L1,L2}, all stride 256
__device__ __forceinline__ int seg_bbase(int s)  { return (s == 1) ? 391 : (s == 3) ? 470 : 0; }
__device__ __forceinline__ int seg_colofs(int s) { return (s == 2) ? XROW_H1 : (s == 4) ? XROW_H2 : 0; }

__device__ __forceinline__ void seg_of(int i, const int* nnzbase, int& seg, int& li) {
    int s = 0;
    s += (i >= nnzbase[1]);
    s += (i >= nnzbase[2]);
    s += (i >= nnzbase[3]);
    s += (i >= nnzbase[4]);
    seg = s; li = i - nnzbase[s];
}

// ---------------- Phase A: LDS-binned partition into bucket arena ----------------
// TILE=2048 (8 entries/thread); col/val cached in regs from pass 1 (no 2nd global read).
// LDS ~29 KB -> 5 blocks/CU.
__global__ __launch_bounds__(256, 5) void partition_kernel(
    BuildArgs a, int* __restrict__ gcursor, int2* __restrict__ arena)
{
    __shared__ int2 staging[TILE];              // 16 KB
    __shared__ unsigned short posb[TILE];       // 4 KB
    __shared__ int  hist[NB];
    __shared__ int  excl[NB + 1];
    __shared__ int  cursor[NB];
    __shared__ int  gofs[NB];                   // gbase[b] - excl[b]

    const int t = threadIdx.x;
    const int tile_base = blockIdx.x * TILE;
    const int total = a.nnzbase[5];
    int tile_n = total - tile_base;
    if (tile_n > TILE) tile_n = TILE;
    if (tile_n <= 0) return;

    for (int i = t; i < NB; i += 256) hist[i] = 0;
    __syncthreads();

    // pass 1: read rows+cols+vals ONCE, histogram, cache everything in regs
    int   pk[EPT];
    int   pcol[EPT];
    float pval[EPT];
#pragma unroll
    for (int q = 0; q < EPT; ++q) {
        int j = t + q * 256;
        pk[q] = -1;
        if (j < tile_n) {
            int i = tile_base + j;
            int seg, li; seg_of(i, a.nnzbase, seg, li);
            int row = a.rows[seg][li];
            pcol[q] = a.cols[seg][li] + seg_colofs(seg);
            pval[q] = a.vals[seg][li];
            int b = seg_bbase(seg) + (row >> 8);
            pk[q] = (b << 8) | (row & 255);
            atomicAdd(&hist[b], 1);
        }
    }
    __syncthreads();

    // wave 0: exclusive scan of hist -> excl
    if (t < 64) {
        int carry = 0;
        for (int base = 0; base < NB; base += 64) {
            int idx = base + t;
            int v = (idx < NB) ? hist[idx] : 0;
            int inc = v;
            for (int d = 1; d < 64; d <<= 1) {
                int u = __shfl_up(inc, d, 64);
                if (t >= d) inc += u;
            }
            if (idx < NB) excl[idx] = carry + inc - v;
            carry += __shfl(inc, 63, 64);
        }
        if (t == 0) excl[NB] = carry;
    }
    __syncthreads();

    // reserve global arena ranges; init cursors; fill posb (fused loop)
    for (int b = t; b < NB; b += 256) {
        int e  = excl[b];
        int hi = excl[b + 1];
        int c  = hi - e;
        int gb = (c > 0) ? atomicAdd(&gcursor[b], c) : 0;
        cursor[b] = e;
        gofs[b] = gb - e;
        for (int p = e; p < hi; ++p) posb[p] = (unsigned short)b;
    }
    __syncthreads();

    // pass 2: scatter from regs into LDS staging grouped by bucket
#pragma unroll
    for (int q = 0; q < EPT; ++q) {
        if (pk[q] >= 0) {
            int b  = pk[q] >> 8;
            int rl = pk[q] & 255;
            int pos = atomicAdd(&cursor[b], 1);
            staging[pos] = make_int2((rl << 18) | pcol[q], __float_as_int(pval[q]));
        }
    }
    __syncthreads();

    // flush: contiguous, position-ordered writes
    for (int p = t; p < tile_n; p += 256) {
        int b = posb[p];
        int reg = bucket_region(b);
        long long slot = reg_arenabase(reg) + (long long)(b - reg_bucketbase(reg)) * reg_cap(reg);
        arena[slot + gofs[b] + p] = staging[p];
    }
}

// ---------------- bucket-count exclusive scan (+rp sentinels) ----------------
__global__ __launch_bounds__(1024) void bucket_scan_kernel(
    const int* __restrict__ gcursor, int* __restrict__ bbase, int* __restrict__ rp)
{
    __shared__ int tmp[1024];
    int t = threadIdx.x;
    int v = (t < NB) ? gcursor[t] : 0;
    tmp[t] = v;
    __syncthreads();
    for (int d = 1; d < 1024; d <<= 1) {
        int u = (t >= d) ? tmp[t - d] : 0;
        __syncthreads();
        tmp[t] += u;
        __syncthreads();
    }
    if (t < NB) bbase[t] = tmp[t] - v;
    // region sentinels
    if (t == 391) rp[RP_S2 + 100000] = tmp[t] - v;   // end of S2
    if (t == 470) rp[RP_P1 + 20000]  = tmp[t] - v;   // end of P1
    if (t == NB - 1) rp[RP_L1 + 20000] = tmp[t];     // total
}

// ---------------- Phase B: per-bucket counting sort -> final cv + rp ----------------
__global__ __launch_bounds__(256) void bucket_sort_kernel(
    const int* __restrict__ gcursor, const int* __restrict__ bbase,
    const int2* __restrict__ arena, int2* __restrict__ cv, int* __restrict__ rp)
{
    __shared__ int hist[256];
    __shared__ int excl[256];
    __shared__ int wsum[4];

    const int b = blockIdx.x;
    const int t = threadIdx.x;
    const int reg = bucket_region(b);
    const int lb = b - reg_bucketbase(reg);
    const int row_base_local = lb << 8;
    int nrows = reg_rows(reg) - row_base_local;
    if (nrows > 256) nrows = 256;
    const long long slot = reg_arenabase(reg) + (long long)lb * reg_cap(reg);
    const int count = gcursor[b];
    const int fbase = bbase[b];

    hist[t] = 0;
    __syncthreads();

    for (int j = t; j < count; j += 256) {
        int key = arena[slot + j].x;
        atomicAdd(&hist[key >> 18], 1);
    }
    __syncthreads();

    // exclusive scan of 256 bins (1 per thread)
    {
        const int lane = t & 63, wave = t >> 6;
        int v = hist[t];
        int inc = v;
        for (int d = 1; d < 64; d <<= 1) {
            int u = __shfl_up(inc, d, 64);
            if (lane >= d) inc += u;
        }
        if (lane == 63) wsum[wave] = inc;
        __syncthreads();
        int woff = 0;
        for (int w = 0; w < wave; ++w) woff += wsum[w];
        excl[t] = woff + inc - v;
    }
    __syncthreads();

    if (t < nrows)
        rp[reg_rpbase(reg) + row_base_local + t] = fbase + excl[t];
    __syncthreads();

    for (int j = t; j < count; j += 256) {
        int2 e = arena[slot + j];
        int r = e.x >> 18;
        int pos = atomicAdd(&excl[r], 1);
        cv[fbase + pos] = make_int2(e.x & 0x3FFFF, e.y);
    }
}

// ---------------- SpMM gather walk: group-of-8, 16 B/lane, int8 x, scale fold ----------------
__device__ __forceinline__ void walk_row8(
    const int2* __restrict__ cv, int start, int end, int lane,
    const unsigned* __restrict__ xq, const float* __restrict__ xs, float* acc)
{
    const int g = lane >> 3;
    const int s = lane & 7;

    for (int sb = start; sb < end; sb += 64) {
        int nn = end - sb; if (nn > 64) nn = 64;
        int2 mycv = make_int2(0, 0);
        float myv = 0.0f;
        if (lane < nn) {
            mycv = cv[sb + lane];
            myv = __int_as_float(mycv.y) * xs[mycv.x];
        }
        const int nn1 = nn - 1;
#pragma unroll 2
        for (int jb = 0; jb < nn; jb += 8) {
            int idx  = jb + g;
            int idxc = idx < nn1 ? idx : nn1;
            int   cs = __shfl(mycv.x, idxc, 64);
            float vs = __shfl(myv, idxc, 64);
            vs = (idx <= nn1) ? vs : 0.0f;
            const uint4 u = *reinterpret_cast<const uint4*>(xq + cs * 32 + s * 4);
#pragma unroll
            for (int w = 0; w < 4; ++w) {
                unsigned uw = (&u.x)[w];
                acc[w * 4 + 0] = fmaf(vs, i8f(uw, 0), acc[w * 4 + 0]);
                acc[w * 4 + 1] = fmaf(vs, i8f(uw, 1), acc[w * 4 + 1]);
                acc[w * 4 + 2] = fmaf(vs, i8f(uw, 2), acc[w * 4 + 2]);
                acc[w * 4 + 3] = fmaf(vs, i8f(uw, 3), acc[w * 4 + 3]);
            }
        }
    }
}

__device__ __forceinline__ void reduce_groups8(float* acc)
{
#pragma unroll
    for (int e = 0; e < 16; ++e) {
        acc[e] += __shfl_xor(acc[e], 8, 64);
        acc[e] += __shfl_xor(acc[e], 16, 64);
        acc[e] += __shfl_xor(acc[e], 32, 64);
    }
}

// stage 1: h1 = p1 @ ego, h2 = l1 @ ego  (int8 gather -> int8 block-scaled rows of xall)
__global__ __launch_bounds__(256) void spmm_stage1_kernel(
    const int* __restrict__ rp, const int2* __restrict__ cv,
    unsigned* __restrict__ xq, float* __restrict__ xs)
{
    int wid = (blockIdx.x * 256 + threadIdx.x) >> 6;
    int lane = threadIdx.x & 63;
    if (wid >= 2 * N_HE) return;
    int rbase, xrow;
    if (wid < N_HE) { rbase = RP_P1 + wid;           xrow = XROW_H1 + wid; }
    else            { rbase = RP_L1 + (wid - N_HE);  xrow = XROW_H2 + (wid - N_HE); }

    float acc[16];
#pragma unroll
    for (int e = 0; e < 16; ++e) acc[e] = 0.0f;
    walk_row8(cv, rp[rbase], rp[rbase + 1], lane, xq, xs, acc);
    reduce_groups8(acc);

    float m = 0.0f;
#pragma unroll
    for (int e = 0; e < 16; ++e) m = fmaxf(m, fabsf(acc[e]));
    m = fmaxf(m, __shfl_xor(m, 1, 64));
    m = fmaxf(m, __shfl_xor(m, 2, 64));
    m = fmaxf(m, __shfl_xor(m, 4, 64));
    float inv = (m > 0.0f) ? 127.0f / m : 0.0f;

    if (lane < 8) {
        uint4 o;
#pragma unroll
        for (int w = 0; w < 4; ++w) {
            int q0 = __float2int_rn(acc[w * 4 + 0] * inv);
            int q1 = __float2int_rn(acc[w * 4 + 1] * inv);
            int q2 = __float2int_rn(acc[w * 4 + 2] * inv);
            int q3 = __float2int_rn(acc[w * 4 + 3] * inv);
            (&o.x)[w] = (q0 & 255) | ((q1 & 255) << 8) | ((q2 & 255) << 16) | ((q3 & 255) << 24);
        }
        *reinterpret_cast<uint4*>(xq + xrow * 32 + lane * 4) = o;
        if (lane == 0) xs[xrow] = m * (1.0f / 127.0f);
    }
}

// stage 2: side = (A|p2|l2) @ xall  — ONE merged walk per output row
__global__ __launch_bounds__(256) void spmm_stage2_kernel(
    const int* __restrict__ rp, const int2* __restrict__ cv,
    const unsigned* __restrict__ xq, const float* __restrict__ xs,
    float* __restrict__ side)
{
    int wid = (blockIdx.x * 256 + threadIdx.x) >> 6;
    int lane = threadIdx.x & 63;
    if (wid >= N_ENT) return;

    float acc[16];
#pragma unroll
    for (int e = 0; e < 16; ++e) acc[e] = 0.0f;
    walk_row8(cv, rp[wid], rp[wid + 1], lane, xq, xs, acc);
    reduce_groups8(acc);

    if (lane < 8) {
        float* yp = side + (long long)wid * DD + lane * 16;
#pragma unroll
        for (int w = 0; w < 4; ++w)
            *reinterpret_cast<float4*>(yp + w * 4) =
                make_float4(acc[w * 4], acc[w * 4 + 1], acc[w * 4 + 2], acc[w * 4 + 3]);
    }
}

// ---------------- MFMA dense epilogue (512 threads, 16 rows/wave) ----------------
union BfFrag { unsigned u[4]; bf16x8 v; };

__global__ __launch_bounds__(512, 4) void dense_mfma_kernel(
    const float* __restrict__ ego, const float* __restrict__ side,
    const float* __restrict__ W1, const float* __restrict__ b1,
    const float* __restrict__ W2, const float* __restrict__ b2,
    float* __restrict__ out)
{
    __shared__ unsigned Wb1[8192];   // 32 KB: W1 bf16, swizzled
    __shared__ unsigned Wb2[8192];   // 32 KB: W2 bf16, swizzled

    const int tid = threadIdx.x;

    for (int idx = tid; idx < 8192; idx += 512) {
        int row = idx >> 6, pc = idx & 63;
        unsigned pk1 = pack_bf16(W1[row * 128 + pc * 2], W1[row * 128 + pc * 2 + 1]);
        unsigned pk2 = pack_bf16(W2[row * 128 + pc * 2], W2[row * 128 + pc * 2 + 1]);
        int boff = row * 256 + ((pc * 4) ^ ((row & 7) << 4));
        *(unsigned*)((char*)Wb1 + boff) = pk1;
        *(unsigned*)((char*)Wb2 + boff) = pk2;
    }
    __syncthreads();

    const int wave = tid >> 6;   // 0..7
    const int lane = tid & 63;
    const int m    = lane & 15;
    const int kg   = lane >> 4;

    float bs[8], bb[8];
#pragma unroll
    for (int c = 0; c < 8; ++c) {
        bs[c] = b1[c * 16 + m];
        bb[c] = b2[c * 16 + m];
    }

    for (int wt = blockIdx.x * 8 + wave; wt < 6250; wt += gridDim.x * 8) {
        const long long r0 = (long long)(wt * 16 + m) * DD;

        f32x4 accS[8], accB[8];
#pragma unroll
        for (int c = 0; c < 8; ++c) { accS[c] = (f32x4)0.0f; accB[c] = (f32x4)0.0f; }

#pragma unroll 1
        for (int kk = 0; kk < 4; ++kk) {
            const int kb = kk * 32 + kg * 8;

            float4 ea = *(const float4*)(ego  + r0 + kb);
            float4 eb = *(const float4*)(ego  + r0 + kb + 4);
            float4 sa = *(const float4*)(side + r0 + kb);
            float4 sb = *(const float4*)(side + r0 + kb + 4);

            BfFrag aS, aB;
            aS.u[0] = pack_bf16(ea.x + sa.x, ea.y + sa.y);
            aS.u[1] = pack_bf16(ea.z + sa.z, ea.w + sa.w);
            aS.u[2] = pack_bf16(eb.x + sb.x, eb.y + sb.y);
            aS.u[3] = pack_bf16(eb.z + sb.z, eb.w + sb.w);
            aB.u[0] = pack_bf16(ea.x * sa.x, ea.y * sa.y);
            aB.u[1] = pack_bf16(ea.z * sa.z, ea.w * sa.w);
            aB.u[2] = pack_bf16(eb.x * sb.x, eb.y * sb.y);
            aB.u[3] = pack_bf16(eb.z * sb.z, eb.w * sb.w);

#pragma unroll
            for (int c = 0; c < 8; ++c) {
                int wrow = c * 16 + m;
                int boff = wrow * 256 + ((kk * 64 + (kg << 4)) ^ ((wrow & 7) << 4));
                bf16x8 w1 = *(const bf16x8*)((const char*)Wb1 + boff);
                bf16x8 w2 = *(const bf16x8*)((const char*)Wb2 + boff);
                accS[c] = __builtin_amdgcn_mfma_f32_16x16x32_bf16(aS.v, w1, accS[c], 0, 0, 0);
                accB[c] = __builtin_amdgcn_mfma_f32_16x16x32_bf16(aB.v, w2, accB[c], 0, 0, 0);
            }
        }

        // D mapping: col = lane&15 (=m), row = kg*4 + q
#pragma unroll
        for (int c = 0; c < 8; ++c) {
#pragma unroll
            for (int q = 0; q < 4; ++q) {
                int orow = wt * 16 + kg * 4 + q;
                out[(long long)orow * DD + c * 16 + m] =
                    lrelu(accS[c][q] + bs[c]) + lrelu(accB[c][q] + bb[c]);
            }
        }
    }
}

extern "C" void kernel_launch(void* const* d_in, const int* in_sizes, int n_in,
                              void* d_out, int out_size, void* d_ws, size_t ws_size,
                              hipStream_t stream)
{
    const float* ego = (const float*)d_in[0];
    const float* W1  = (const float*)d_in[16];
    const float* b1  = (const float*)d_in[17];
    const float* W2  = (const float*)d_in[18];
    const float* b2  = (const float*)d_in[19];

    BuildArgs a;
    a.rows[0] = (const int*)d_in[1];  a.cols[0] = (const int*)d_in[2];  a.vals[0] = (const float*)d_in[3];
    a.rows[1] = (const int*)d_in[4];  a.cols[1] = (const int*)d_in[5];  a.vals[1] = (const float*)d_in[6];
    a.rows[2] = (const int*)d_in[7];  a.cols[2] = (const int*)d_in[8];  a.vals[2] = (const float*)d_in[9];
    a.rows[3] = (const int*)d_in[10]; a.cols[3] = (const int*)d_in[11]; a.vals[3] = (const float*)d_in[12];
    a.rows[4] = (const int*)d_in[13]; a.cols[4] = (const int*)d_in[14]; a.vals[4] = (const float*)d_in[15];
    int nnz[5] = { in_sizes[1], in_sizes[4], in_sizes[7], in_sizes[10], in_sizes[13] };
    a.nnzbase[0] = 0;
    for (int s = 0; s < 5; ++s) a.nnzbase[s + 1] = a.nnzbase[s] + nnz[s];
    const int total = a.nnzbase[5];

    // ---- workspace carve (arena time-shares the side region; arena = 49.5 MB) ----
    char* p = (char*)d_ws;
    float*    side    = (float*)p;
    int2*     arena   = (int2*)p;         p += (size_t)N_ENT * DD * 4;       // 51.2 MB
    unsigned* xq      = (unsigned*)p;     p += (size_t)140032 * 32 * 4;      // 17.9 MB (int8 rows x 140K)
    float*    xs      = (float*)p;        p += (size_t)140032 * 4;           // 560 KB
    int2*     cv      = (int2*)p;         p += (size_t)total * 8;            // 44.8 MB
    int*      rp      = (int*)p;          p += 141056 * 4;
    int*      gcursor = (int*)p;          p += 1024 * 4;
    int*      bbase   = (int*)p;          p += 1024 * 4;

    // build
    hipMemsetAsync(gcursor, 0, NB * sizeof(int), stream);
    quant_ego_kernel<<<(N_ENT * 32 + 255) / 256, 256, 0, stream>>>(ego, xq, xs);
    const int nblk_part = (total + TILE - 1) / TILE;
    partition_kernel<<<nblk_part, 256, 0, stream>>>(a, gcursor, arena);
    bucket_scan_kernel<<<1, 1024, 0, stream>>>(gcursor, bbase, rp);
    bucket_sort_kernel<<<NB, 256, 0, stream>>>(gcursor, bbase, arena, cv, rp);

    // spmm (arena region is dead from here; side reuses it)
    spmm_stage1_kernel<<<(2 * N_HE) / 4, 256, 0, stream>>>(rp, cv, xq, xs);
    spmm_stage2_kernel<<<N_ENT / 4, 256, 0, stream>>>(rp, cv, xq, xs, side);

    // dense epilogue (MFMA, 512-thread blocks)
    dense_mfma_kernel<<<782, 512, 0, stream>>>(ego, side, W1, b1, W2, b2, (float*)d_out);
}

// Round 13
// 307.463 us; speedup vs baseline: 1.2270x; 1.0231x over previous
//
#include <hip/hip_runtime.h>

#define N_ENT 100000
#define N_HE  20000
#define DD    128

// Unified x-space rows: ego 0..100000, h1 100000..120000, h2 120000..140000
#define XROW_H1 100000
#define XROW_H2 120000

// rp row spaces
#define RP_S2  0
#define RP_P1  100001
#define RP_L1  120002

// Bucket geometry:
// region 0 = S2 (A+P2+L2 merged): 196 buckets, stride 512, cap 19968
// region 1 = P1: 79 buckets, stride 256, cap 13824
// region 2 = L1: 79 buckets, stride 256, cap 13824
#define NB 354
#define TILE 3072
#define EPT  12   // entries per thread = TILE/256

typedef float f32x4 __attribute__((ext_vector_type(4)));
typedef short bf16x8 __attribute__((ext_vector_type(8)));

__device__ __forceinline__ int bucket_region(int b) {
    return (b < 196) ? 0 : (b < 275) ? 1 : 2;
}
__device__ __forceinline__ int reg_shift(int r)      { return r == 0 ? 9 : 8; }
__device__ __forceinline__ int reg_bucketbase(int r) { return r == 0 ? 0 : r == 1 ? 196 : 275; }
__device__ __forceinline__ int reg_cap(int r)        { return r == 0 ? 19968 : 13824; }
__device__ __forceinline__ long long reg_arenabase(int r) {
    return r == 0 ? 0LL : r == 1 ? 3913728LL : 5005824LL;   // 196*19968 ; +79*13824
}
__device__ __forceinline__ int reg_rpbase(int r)     { return r == 0 ? RP_S2 : r == 1 ? RP_P1 : RP_L1; }
__device__ __forceinline__ int reg_rows(int r)       { return r == 0 ? 100000 : 20000; }

__device__ __forceinline__ unsigned short f2bf(float f) {
    unsigned u = __float_as_uint(f);
    unsigned r = (u + 0x7fffu + ((u >> 16) & 1u)) >> 16;   // RNE
    return (unsigned short)r;
}
__device__ __forceinline__ unsigned pack_bf16(float a, float b) {
    return (unsigned)f2bf(a) | ((unsigned)f2bf(b) << 16);
}
__device__ __forceinline__ float lrelu(float x) { return x > 0.0f ? x : 0.01f * x; }
__device__ __forceinline__ float i8f(unsigned u, int b) {
    return (float)((int)(u << (24 - 8 * b)) >> 24);
}

// ---------------- ego fp32 -> block-scaled int8 rows of xall ----------------
__global__ __launch_bounds__(256) void quant_ego_kernel(
    const float* __restrict__ ego, unsigned* __restrict__ xq,
    float* __restrict__ xs)
{
    int row = (blockIdx.x * 256 + threadIdx.x) >> 5;
    if (row >= N_ENT) return;
    int l = threadIdx.x & 31;
    const float4 v = *(const float4*)(ego + (long long)row * DD + l * 4);
    float m = fmaxf(fmaxf(fabsf(v.x), fabsf(v.y)), fmaxf(fabsf(v.z), fabsf(v.w)));
    for (int d = 1; d < 32; d <<= 1) m = fmaxf(m, __shfl_xor(m, d, 32));
    float inv = (m > 0.0f) ? 127.0f / m : 0.0f;
    int q0 = __float2int_rn(v.x * inv);
    int q1 = __float2int_rn(v.y * inv);
    int q2 = __float2int_rn(v.z * inv);
    int q3 = __float2int_rn(v.w * inv);
    unsigned pk = (q0 & 255) | ((q1 & 255) << 8) | ((q2 & 255) << 16) | ((q3 & 255) << 24);
    xq[row * 32 + l] = pk;
    if (l == 0) xs[row] = m * (1.0f / 127.0f);
}

struct BuildArgs {
    const int*   rows[5];
    const int*   cols[5];
    const float* vals[5];
    int nnzbase[6];
};

// seg -> bucket mapping: {A,P1,P2,L1,L2}
__device__ __forceinline__ int seg_bbase(int s)  { return (s == 1) ? 196 : (s == 3) ? 275 : 0; }
__device__ __forceinline__ int seg_shift2(int s) { return (s == 1 || s == 3) ? 8 : 9; }
__device__ __forceinline__ int seg_colofs(int s) { return (s == 2) ? XROW_H1 : (s == 4) ? XROW_H2 : 0; }

__device__ __forceinline__ void seg_of(int i, const int* nnzbase, int& seg, int& li) {
    int s = 0;
    s += (i >= nnzbase[1]);
    s += (i >= nnzbase[2]);
    s += (i >= nnzbase[3]);
    s += (i >= nnzbase[4]);
    seg = s; li = i - nnzbase[s];
}

// ---------------- Phase A: LDS-binned partition into bucket arena ----------------
// TILE=3072 (12 entries/thread); row/col/val cached in regs from pass 1.
// Stride-512 S2 buckets -> ~8.7-entry (70 B) flush runs. LDS ~36 KB -> 4 blocks/CU.
__global__ __launch_bounds__(256, 4) void partition_kernel(
    BuildArgs a, int* __restrict__ gcursor, int2* __restrict__ arena)
{
    __shared__ int2 staging[TILE];              // 24 KB
    __shared__ unsigned short posb[TILE];       // 6 KB
    __shared__ int  hist[NB];
    __shared__ int  excl[NB + 1];
    __shared__ int  cursor[NB];
    __shared__ int  gofs[NB];                   // gbase[b] - excl[b]

    const int t = threadIdx.x;
    const int tile_base = blockIdx.x * TILE;
    const int total = a.nnzbase[5];
    int tile_n = total - tile_base;
    if (tile_n > TILE) tile_n = TILE;
    if (tile_n <= 0) return;

    for (int i = t; i < NB; i += 256) hist[i] = 0;
    __syncthreads();

    // pass 1: read rows+cols+vals ONCE, histogram, cache everything in regs
    int   pk[EPT];
    int   pcol[EPT];
    float pval[EPT];
#pragma unroll
    for (int q = 0; q < EPT; ++q) {
        int j = t + q * 256;
        pk[q] = -1;
        if (j < tile_n) {
            int i = tile_base + j;
            int seg, li; seg_of(i, a.nnzbase, seg, li);
            int row = a.rows[seg][li];
            pcol[q] = a.cols[seg][li] + seg_colofs(seg);
            pval[q] = a.vals[seg][li];
            int sh = seg_shift2(seg);
            int b = seg_bbase(seg) + (row >> sh);
            pk[q] = (b << 9) | (row & ((1 << sh) - 1));
            atomicAdd(&hist[b], 1);
        }
    }
    __syncthreads();

    // wave 0: exclusive scan of hist -> excl
    if (t < 64) {
        int carry = 0;
        for (int base = 0; base < NB; base += 64) {
            int idx = base + t;
            int v = (idx < NB) ? hist[idx] : 0;
            int inc = v;
            for (int d = 1; d < 64; d <<= 1) {
                int u = __shfl_up(inc, d, 64);
                if (t >= d) inc += u;
            }
            if (idx < NB) excl[idx] = carry + inc - v;
            carry += __shfl(inc, 63, 64);
        }
        if (t == 0) excl[NB] = carry;
    }
    __syncthreads();

    // reserve global arena ranges; init cursors; fill posb (fused loop)
    for (int b = t; b < NB; b += 256) {
        int e  = excl[b];
        int hi = excl[b + 1];
        int c  = hi - e;
        int gb = (c > 0) ? atomicAdd(&gcursor[b], c) : 0;
        cursor[b] = e;
        gofs[b] = gb - e;
        for (int p = e; p < hi; ++p) posb[p] = (unsigned short)b;
    }
    __syncthreads();

    // pass 2: scatter from regs into LDS staging grouped by bucket
#pragma unroll
    for (int q = 0; q < EPT; ++q) {
        if (pk[q] >= 0) {
            int b  = pk[q] >> 9;
            int rl = pk[q] & 511;
            int pos = atomicAdd(&cursor[b], 1);
            staging[pos] = make_int2((rl << 18) | pcol[q], __float_as_int(pval[q]));
        }
    }
    __syncthreads();

    // flush: contiguous, position-ordered writes
    for (int p = t; p < tile_n; p += 256) {
        int b = posb[p];
        int reg = bucket_region(b);
        long long slot = reg_arenabase(reg) + (long long)(b - reg_bucketbase(reg)) * reg_cap(reg);
        arena[slot + gofs[b] + p] = staging[p];
    }
}

// ---------------- bucket-count exclusive scan (+rp sentinels) ----------------
__global__ __launch_bounds__(512) void bucket_scan_kernel(
    const int* __restrict__ gcursor, int* __restrict__ bbase, int* __restrict__ rp)
{
    __shared__ int tmp[512];
    int t = threadIdx.x;
    int v = (t < NB) ? gcursor[t] : 0;
    tmp[t] = v;
    __syncthreads();
    for (int d = 1; d < 512; d <<= 1) {
        int u = (t >= d) ? tmp[t - d] : 0;
        __syncthreads();
        tmp[t] += u;
        __syncthreads();
    }
    if (t < NB) bbase[t] = tmp[t] - v;
    // region sentinels
    if (t == 196) rp[RP_S2 + 100000] = tmp[t] - v;   // end of S2
    if (t == 275) rp[RP_P1 + 20000]  = tmp[t] - v;   // end of P1
    if (t == NB - 1) rp[RP_L1 + 20000] = tmp[t];     // total
}

// ---------------- Phase B: per-bucket counting sort -> final cv + rp ----------------
__global__ __launch_bounds__(256) void bucket_sort_kernel(
    const int* __restrict__ gcursor, const int* __restrict__ bbase,
    const int2* __restrict__ arena, int2* __restrict__ cv, int* __restrict__ rp)
{
    __shared__ int hist[512];
    __shared__ int excl[512];
    __shared__ int wsum[4];

    const int b = blockIdx.x;
    const int t = threadIdx.x;
    const int reg = bucket_region(b);
    const int sh = reg_shift(reg);
    const int stride = 1 << sh;
    const int lb = b - reg_bucketbase(reg);
    const int row_base_local = lb << sh;
    int nrows = reg_rows(reg) - row_base_local;
    if (nrows > stride) nrows = stride;
    const long long slot = reg_arenabase(reg) + (long long)lb * reg_cap(reg);
    const int count = gcursor[b];
    const int fbase = bbase[b];

    for (int i = t; i < 512; i += 256) hist[i] = 0;
    __syncthreads();

    for (int j = t; j < count; j += 256) {
        int key = arena[slot + j].x;
        atomicAdd(&hist[key >> 18], 1);
    }
    __syncthreads();

    // exclusive scan of 512 bins (2 per thread)
    {
        const int lane = t & 63, wave = t >> 6;
        int v0 = hist[t * 2], v1 = hist[t * 2 + 1];
        int s = v0 + v1;
        int inc = s;
        for (int d = 1; d < 64; d <<= 1) {
            int u = __shfl_up(inc, d, 64);
            if (lane >= d) inc += u;
        }
        if (lane == 63) wsum[wave] = inc;
        __syncthreads();
        int woff = 0;
        for (int w = 0; w < wave; ++w) woff += wsum[w];
        int run = woff + inc - s;
        excl[t * 2] = run;
        excl[t * 2 + 1] = run + v0;
    }
    __syncthreads();

    const int grow0 = reg_rpbase(reg) + row_base_local;
    for (int r = t; r < nrows; r += 256)
        rp[grow0 + r] = fbase + excl[r];
    __syncthreads();

    for (int j = t; j < count; j += 256) {
        int2 e = arena[slot + j];
        int r = e.x >> 18;
        int pos = atomicAdd(&excl[r], 1);
        cv[fbase + pos] = make_int2(e.x & 0x3FFFF, e.y);
    }
}

// ---------------- SpMM gather walk: group-of-8, 16 B/lane, int8 x, scale fold ----------------
// Lane l: group g = l>>3 handles nnz jb+g; sublane s = l&7 loads 16 B of the row.
// acc[16] covers dims s*16 .. s*16+15. One wave-load = 8 nnz (8 lines, 1 KB).
// unroll 4 -> up to 4 KB outstanding per wave (latency hiding).
__device__ __forceinline__ void walk_row8(
    const int2* __restrict__ cv, int start, int end, int lane,
    const unsigned* __restrict__ xq, const float* __restrict__ xs, float* acc)
{
    const int g = lane >> 3;
    const int s = lane & 7;

    for (int sb = start; sb < end; sb += 64) {
        int nn = end - sb; if (nn > 64) nn = 64;
        int2 mycv = make_int2(0, 0);
        float myv = 0.0f;
        if (lane < nn) {
            mycv = cv[sb + lane];
            myv = __int_as_float(mycv.y) * xs[mycv.x];
        }
        const int nn1 = nn - 1;
#pragma unroll 4
        for (int jb = 0; jb < nn; jb += 8) {
            int idx  = jb + g;
            int idxc = idx < nn1 ? idx : nn1;
            int   cs = __shfl(mycv.x, idxc, 64);
            float vs = __shfl(myv, idxc, 64);
            vs = (idx <= nn1) ? vs : 0.0f;
            const uint4 u = *reinterpret_cast<const uint4*>(xq + cs * 32 + s * 4);
#pragma unroll
            for (int w = 0; w < 4; ++w) {
                unsigned uw = (&u.x)[w];
                acc[w * 4 + 0] = fmaf(vs, i8f(uw, 0), acc[w * 4 + 0]);
                acc[w * 4 + 1] = fmaf(vs, i8f(uw, 1), acc[w * 4 + 1]);
                acc[w * 4 + 2] = fmaf(vs, i8f(uw, 2), acc[w * 4 + 2]);
                acc[w * 4 + 3] = fmaf(vs, i8f(uw, 3), acc[w * 4 + 3]);
            }
        }
    }
}

__device__ __forceinline__ void reduce_groups8(float* acc)
{
#pragma unroll
    for (int e = 0; e < 16; ++e) {
        acc[e] += __shfl_xor(acc[e], 8, 64);
        acc[e] += __shfl_xor(acc[e], 16, 64);
        acc[e] += __shfl_xor(acc[e], 32, 64);
    }
}

// stage 1: h1 = p1 @ ego, h2 = l1 @ ego  (int8 gather -> int8 block-scaled rows of xall)
__global__ __launch_bounds__(256) void spmm_stage1_kernel(
    const int* __restrict__ rp, const int2* __restrict__ cv,
    unsigned* __restrict__ xq, float* __restrict__ xs)
{
    int wid = (blockIdx.x * 256 + threadIdx.x) >> 6;
    int lane = threadIdx.x & 63;
    if (wid >= 2 * N_HE) return;
    int rbase, xrow;
    if (wid < N_HE) { rbase = RP_P1 + wid;           xrow = XROW_H1 + wid; }
    else            { rbase = RP_L1 + (wid - N_HE);  xrow = XROW_H2 + (wid - N_HE); }

    float acc[16];
#pragma unroll
    for (int e = 0; e < 16; ++e) acc[e] = 0.0f;
    walk_row8(cv, rp[rbase], rp[rbase + 1], lane, xq, xs, acc);
    reduce_groups8(acc);

    float m = 0.0f;
#pragma unroll
    for (int e = 0; e < 16; ++e) m = fmaxf(m, fabsf(acc[e]));
    m = fmaxf(m, __shfl_xor(m, 1, 64));
    m = fmaxf(m, __shfl_xor(m, 2, 64));
    m = fmaxf(m, __shfl_xor(m, 4, 64));
    float inv = (m > 0.0f) ? 127.0f / m : 0.0f;

    if (lane < 8) {
        uint4 o;
#pragma unroll
        for (int w = 0; w < 4; ++w) {
            int q0 = __float2int_rn(acc[w * 4 + 0] * inv);
            int q1 = __float2int_rn(acc[w * 4 + 1] * inv);
            int q2 = __float2int_rn(acc[w * 4 + 2] * inv);
            int q3 = __float2int_rn(acc[w * 4 + 3] * inv);
            (&o.x)[w] = (q0 & 255) | ((q1 & 255) << 8) | ((q2 & 255) << 16) | ((q3 & 255) << 24);
        }
        *reinterpret_cast<uint4*>(xq + xrow * 32 + lane * 4) = o;
        if (lane == 0) xs[xrow] = m * (1.0f / 127.0f);
    }
}

// stage 2: side = (A|p2|l2) @ xall  — ONE merged walk per output row
__global__ __launch_bounds__(256) void spmm_stage2_kernel(
    const int* __restrict__ rp, const int2* __restrict__ cv,
    const unsigned* __restrict__ xq, const float* __restrict__ xs,
    float* __restrict__ side)
{
    int wid = (blockIdx.x * 256 + threadIdx.x) >> 6;
    int lane = threadIdx.x & 63;
    if (wid >= N_ENT) return;

    float acc[16];
#pragma unroll
    for (int e = 0; e < 16; ++e) acc[e] = 0.0f;
    walk_row8(cv, rp[wid], rp[wid + 1], lane, xq, xs, acc);
    reduce_groups8(acc);

    if (lane < 8) {
        float* yp = side + (long long)wid * DD + lane * 16;
#pragma unroll
        for (int w = 0; w < 4; ++w)
            *reinterpret_cast<float4*>(yp + w * 4) =
                make_float4(acc[w * 4], acc[w * 4 + 1], acc[w * 4 + 2], acc[w * 4 + 3]);
    }
}

// ---------------- MFMA dense epilogue (512 threads, 16 rows/wave) ----------------
union BfFrag { unsigned u[4]; bf16x8 v; };

__global__ __launch_bounds__(512, 4) void dense_mfma_kernel(
    const float* __restrict__ ego, const float* __restrict__ side,
    const float* __restrict__ W1, const float* __restrict__ b1,
    const float* __restrict__ W2, const float* __restrict__ b2,
    float* __restrict__ out)
{
    __shared__ unsigned Wb1[8192];   // 32 KB: W1 bf16, swizzled
    __shared__ unsigned Wb2[8192];   // 32 KB: W2 bf16, swizzled

    const int tid = threadIdx.x;

    for (int idx = tid; idx < 8192; idx += 512) {
        int row = idx >> 6, pc = idx & 63;
        unsigned pk1 = pack_bf16(W1[row * 128 + pc * 2], W1[row * 128 + pc * 2 + 1]);
        unsigned pk2 = pack_bf16(W2[row * 128 + pc * 2], W2[row * 128 + pc * 2 + 1]);
        int boff = row * 256 + ((pc * 4) ^ ((row & 7) << 4));
        *(unsigned*)((char*)Wb1 + boff) = pk1;
        *(unsigned*)((char*)Wb2 + boff) = pk2;
    }
    __syncthreads();

    const int wave = tid >> 6;   // 0..7
    const int lane = tid & 63;
    const int m    = lane & 15;
    const int kg   = lane >> 4;

    float bs[8], bb[8];
#pragma unroll
    for (int c = 0; c < 8; ++c) {
        bs[c] = b1[c * 16 + m];
        bb[c] = b2[c * 16 + m];
    }

    for (int wt = blockIdx.x * 8 + wave; wt < 6250; wt += gridDim.x * 8) {
        const long long r0 = (long long)(wt * 16 + m) * DD;

        f32x4 accS[8], accB[8];
#pragma unroll
        for (int c = 0; c < 8; ++c) { accS[c] = (f32x4)0.0f; accB[c] = (f32x4)0.0f; }

#pragma unroll 1
        for (int kk = 0; kk < 4; ++kk) {
            const int kb = kk * 32 + kg * 8;

            float4 ea = *(const float4*)(ego  + r0 + kb);
            float4 eb = *(const float4*)(ego  + r0 + kb + 4);
            float4 sa = *(const float4*)(side + r0 + kb);
            float4 sb = *(const float4*)(side + r0 + kb + 4);

            BfFrag aS, aB;
            aS.u[0] = pack_bf16(ea.x + sa.x, ea.y + sa.y);
            aS.u[1] = pack_bf16(ea.z + sa.z, ea.w + sa.w);
            aS.u[2] = pack_bf16(eb.x + sb.x, eb.y + sb.y);
            aS.u[3] = pack_bf16(eb.z + sb.z, eb.w + sb.w);
            aB.u[0] = pack_bf16(ea.x * sa.x, ea.y * sa.y);
            aB.u[1] = pack_bf16(ea.z * sa.z, ea.w * sa.w);
            aB.u[2] = pack_bf16(eb.x * sb.x, eb.y * sb.y);
            aB.u[3] = pack_bf16(eb.z * sb.z, eb.w * sb.w);

#pragma unroll
            for (int c = 0; c < 8; ++c) {
                int wrow = c * 16 + m;
                int boff = wrow * 256 + ((kk * 64 + (kg << 4)) ^ ((wrow & 7) << 4));
                bf16x8 w1 = *(const bf16x8*)((const char*)Wb1 + boff);
                bf16x8 w2 = *(const bf16x8*)((const char*)Wb2 + boff);
                accS[c] = __builtin_amdgcn_mfma_f32_16x16x32_bf16(aS.v, w1, accS[c], 0, 0, 0);
                accB[c] = __builtin_amdgcn_mfma_f32_16x16x32_bf16(aB.v, w2, accB[c], 0, 0, 0);
            }
        }

        // D mapping: col = lane&15 (=m), row = kg*4 + q
#pragma unroll
        for (int c = 0; c < 8; ++c) {
#pragma unroll
            for (int q = 0; q < 4; ++q) {
                int orow = wt * 16 + kg * 4 + q;
                out[(long long)orow * DD + c * 16 + m] =
                    lrelu(accS[c][q] + bs[c]) + lrelu(accB[c][q] + bb[c]);
            }
        }
    }
}

extern "C" void kernel_launch(void* const* d_in, const int* in_sizes, int n_in,
                              void* d_out, int out_size, void* d_ws, size_t ws_size,
                              hipStream_t stream)
{
    const float* ego = (const float*)d_in[0];
    const float* W1  = (const float*)d_in[16];
    const float* b1  = (const float*)d_in[17];
    const float* W2  = (const float*)d_in[18];
    const float* b2  = (const float*)d_in[19];

    BuildArgs a;
    a.rows[0] = (const int*)d_in[1];  a.cols[0] = (const int*)d_in[2];  a.vals[0] = (const float*)d_in[3];
    a.rows[1] = (const int*)d_in[4];  a.cols[1] = (const int*)d_in[5];  a.vals[1] = (const float*)d_in[6];
    a.rows[2] = (const int*)d_in[7];  a.cols[2] = (const int*)d_in[8];  a.vals[2] = (const float*)d_in[9];
    a.rows[3] = (const int*)d_in[10]; a.cols[3] = (const int*)d_in[11]; a.vals[3] = (const float*)d_in[12];
    a.rows[4] = (const int*)d_in[13]; a.cols[4] = (const int*)d_in[14]; a.vals[4] = (const float*)d_in[15];
    int nnz[5] = { in_sizes[1], in_sizes[4], in_sizes[7], in_sizes[10], in_sizes[13] };
    a.nnzbase[0] = 0;
    for (int s = 0; s < 5; ++s) a.nnzbase[s + 1] = a.nnzbase[s] + nnz[s];
    const int total = a.nnzbase[5];

    // ---- workspace carve (arena time-shares the side region; arena = 48.8 MB) ----
    char* p = (char*)d_ws;
    float*    side    = (float*)p;
    int2*     arena   = (int2*)p;         p += (size_t)N_ENT * DD * 4;       // 51.2 MB
    unsigned* xq      = (unsigned*)p;     p += (size_t)140032 * 32 * 4;      // 17.9 MB (int8 rows x 140K)
    float*    xs      = (float*)p;        p += (size_t)140032 * 4;           // 560 KB
    int2*     cv      = (int2*)p;         p += (size_t)total * 8;            // 44.8 MB
    int*      rp      = (int*)p;          p += 141056 * 4;
    int*      gcursor = (int*)p;          p += 1024 * 4;
    int*      bbase   = (int*)p;          p += 1024 * 4;

    // build
    hipMemsetAsync(gcursor, 0, NB * sizeof(int), stream);
    quant_ego_kernel<<<(N_ENT * 32 + 255) / 256, 256, 0, stream>>>(ego, xq, xs);
    const int nblk_part = (total + TILE - 1) / TILE;
    partition_kernel<<<nblk_part, 256, 0, stream>>>(a, gcursor, arena);
    bucket_scan_kernel<<<1, 512, 0, stream>>>(gcursor, bbase, rp);
    bucket_sort_kernel<<<NB, 256, 0, stream>>>(gcursor, bbase, arena, cv, rp);

    // spmm (arena region is dead from here; side reuses it)
    spmm_stage1_kernel<<<(2 * N_HE) / 4, 256, 0, stream>>>(rp, cv, xq, xs);
    spmm_stage2_kernel<<<N_ENT / 4, 256, 0, stream>>>(rp, cv, xq, xs, side);

    // dense epilogue (MFMA, 512-thread blocks)
    dense_mfma_kernel<<<782, 512, 0, stream>>>(ego, side, W1, b1, W2, b2, (float*)d_out);
}

// Round 14
// 304.108 us; speedup vs baseline: 1.2406x; 1.0110x over previous
//
#include <hip/hip_runtime.h>

#define N_ENT 100000
#define N_HE  20000
#define DD    128

// Unified x-space rows: ego 0..100000, h1 100000..120000, h2 120000..140000
#define XROW_H1 100000
#define XROW_H2 120000

// rp row spaces
#define RP_S2  0
#define RP_P1  100001
#define RP_L1  120002

// Bucket geometry:
// region 0 = S2 (A+P2+L2 merged): 196 buckets, stride 512, cap 19968
// region 1 = P1: 79 buckets, stride 256, cap 13824
// region 2 = L1: 79 buckets, stride 256, cap 13824
#define NB 354
#define TILE 3072
#define EPT  12   // entries per thread = TILE/256

typedef float f32x4 __attribute__((ext_vector_type(4)));
typedef short bf16x8 __attribute__((ext_vector_type(8)));

__device__ __forceinline__ int bucket_region(int b) {
    return (b < 196) ? 0 : (b < 275) ? 1 : 2;
}
__device__ __forceinline__ int reg_shift(int r)      { return r == 0 ? 9 : 8; }
__device__ __forceinline__ int reg_bucketbase(int r) { return r == 0 ? 0 : r == 1 ? 196 : 275; }
__device__ __forceinline__ int reg_cap(int r)        { return r == 0 ? 19968 : 13824; }
__device__ __forceinline__ long long reg_arenabase(int r) {
    return r == 0 ? 0LL : r == 1 ? 3913728LL : 5005824LL;   // 196*19968 ; +79*13824
}
__device__ __forceinline__ int reg_rpbase(int r)     { return r == 0 ? RP_S2 : r == 1 ? RP_P1 : RP_L1; }
__device__ __forceinline__ int reg_rows(int r)       { return r == 0 ? 100000 : 20000; }

__device__ __forceinline__ unsigned short f2bf(float f) {
    unsigned u = __float_as_uint(f);
    unsigned r = (u + 0x7fffu + ((u >> 16) & 1u)) >> 16;   // RNE
    return (unsigned short)r;
}
__device__ __forceinline__ unsigned pack_bf16(float a, float b) {
    return (unsigned)f2bf(a) | ((unsigned)f2bf(b) << 16);
}
__device__ __forceinline__ float lrelu(float x) { return x > 0.0f ? x : 0.01f * x; }
__device__ __forceinline__ float i8f(unsigned u, int b) {
    return (float)((int)(u << (24 - 8 * b)) >> 24);
}

// ---------------- ego fp32 -> block-scaled int8 rows of xall ----------------
__global__ __launch_bounds__(256) void quant_ego_kernel(
    const float* __restrict__ ego, unsigned* __restrict__ xq,
    float* __restrict__ xs)
{
    int row = (blockIdx.x * 256 + threadIdx.x) >> 5;
    if (row >= N_ENT) return;
    int l = threadIdx.x & 31;
    const float4 v = *(const float4*)(ego + (long long)row * DD + l * 4);
    float m = fmaxf(fmaxf(fabsf(v.x), fabsf(v.y)), fmaxf(fabsf(v.z), fabsf(v.w)));
    for (int d = 1; d < 32; d <<= 1) m = fmaxf(m, __shfl_xor(m, d, 32));
    float inv = (m > 0.0f) ? 127.0f / m : 0.0f;
    int q0 = __float2int_rn(v.x * inv);
    int q1 = __float2int_rn(v.y * inv);
    int q2 = __float2int_rn(v.z * inv);
    int q3 = __float2int_rn(v.w * inv);
    unsigned pk = (q0 & 255) | ((q1 & 255) << 8) | ((q2 & 255) << 16) | ((q3 & 255) << 24);
    xq[row * 32 + l] = pk;
    if (l == 0) xs[row] = m * (1.0f / 127.0f);
}

struct BuildArgs {
    const int*   rows[5];
    const int*   cols[5];
    const float* vals[5];
    int nnzbase[6];
};

// seg -> bucket mapping: {A,P1,P2,L1,L2}
__device__ __forceinline__ int seg_bbase(int s)  { return (s == 1) ? 196 : (s == 3) ? 275 : 0; }
__device__ __forceinline__ int seg_shift2(int s) { return (s == 1 || s == 3) ? 8 : 9; }
__device__ __forceinline__ int seg_colofs(int s) { return (s == 2) ? XROW_H1 : (s == 4) ? XROW_H2 : 0; }

__device__ __forceinline__ void seg_of(int i, const int* nnzbase, int& seg, int& li) {
    int s = 0;
    s += (i >= nnzbase[1]);
    s += (i >= nnzbase[2]);
    s += (i >= nnzbase[3]);
    s += (i >= nnzbase[4]);
    seg = s; li = i - nnzbase[s];
}

// ---------------- Phase A: LDS-binned partition into bucket arena ----------------
__global__ __launch_bounds__(256, 4) void partition_kernel(
    BuildArgs a, int* __restrict__ gcursor, int2* __restrict__ arena)
{
    __shared__ int2 staging[TILE];              // 24 KB
    __shared__ unsigned short posb[TILE];       // 6 KB
    __shared__ int  hist[NB];
    __shared__ int  excl[NB + 1];
    __shared__ int  cursor[NB];
    __shared__ int  gofs[NB];                   // gbase[b] - excl[b]

    const int t = threadIdx.x;
    const int tile_base = blockIdx.x * TILE;
    const int total = a.nnzbase[5];
    int tile_n = total - tile_base;
    if (tile_n > TILE) tile_n = TILE;
    if (tile_n <= 0) return;

    for (int i = t; i < NB; i += 256) hist[i] = 0;
    __syncthreads();

    // pass 1: read rows+cols+vals ONCE, histogram, cache everything in regs
    int   pk[EPT];
    int   pcol[EPT];
    float pval[EPT];
#pragma unroll
    for (int q = 0; q < EPT; ++q) {
        int j = t + q * 256;
        pk[q] = -1;
        if (j < tile_n) {
            int i = tile_base + j;
            int seg, li; seg_of(i, a.nnzbase, seg, li);
            int row = a.rows[seg][li];
            pcol[q] = a.cols[seg][li] + seg_colofs(seg);
            pval[q] = a.vals[seg][li];
            int sh = seg_shift2(seg);
            int b = seg_bbase(seg) + (row >> sh);
            pk[q] = (b << 9) | (row & ((1 << sh) - 1));
            atomicAdd(&hist[b], 1);
        }
    }
    __syncthreads();

    // wave 0: exclusive scan of hist -> excl
    if (t < 64) {
        int carry = 0;
        for (int base = 0; base < NB; base += 64) {
            int idx = base + t;
            int v = (idx < NB) ? hist[idx] : 0;
            int inc = v;
            for (int d = 1; d < 64; d <<= 1) {
                int u = __shfl_up(inc, d, 64);
                if (t >= d) inc += u;
            }
            if (idx < NB) excl[idx] = carry + inc - v;
            carry += __shfl(inc, 63, 64);
        }
        if (t == 0) excl[NB] = carry;
    }
    __syncthreads();

    // reserve global arena ranges; init cursors; fill posb (fused loop)
    for (int b = t; b < NB; b += 256) {
        int e  = excl[b];
        int hi = excl[b + 1];
        int c  = hi - e;
        int gb = (c > 0) ? atomicAdd(&gcursor[b], c) : 0;
        cursor[b] = e;
        gofs[b] = gb - e;
        for (int p = e; p < hi; ++p) posb[p] = (unsigned short)b;
    }
    __syncthreads();

    // pass 2: scatter from regs into LDS staging grouped by bucket
#pragma unroll
    for (int q = 0; q < EPT; ++q) {
        if (pk[q] >= 0) {
            int b  = pk[q] >> 9;
            int rl = pk[q] & 511;
            int pos = atomicAdd(&cursor[b], 1);
            staging[pos] = make_int2((rl << 18) | pcol[q], __float_as_int(pval[q]));
        }
    }
    __syncthreads();

    // flush: contiguous, position-ordered writes
    for (int p = t; p < tile_n; p += 256) {
        int b = posb[p];
        int reg = bucket_region(b);
        long long slot = reg_arenabase(reg) + (long long)(b - reg_bucketbase(reg)) * reg_cap(reg);
        arena[slot + gofs[b] + p] = staging[p];
    }
}

// ---------------- bucket-count exclusive scan (+rp sentinels) ----------------
__global__ __launch_bounds__(512) void bucket_scan_kernel(
    const int* __restrict__ gcursor, int* __restrict__ bbase, int* __restrict__ rp)
{
    __shared__ int tmp[512];
    int t = threadIdx.x;
    int v = (t < NB) ? gcursor[t] : 0;
    tmp[t] = v;
    __syncthreads();
    for (int d = 1; d < 512; d <<= 1) {
        int u = (t >= d) ? tmp[t - d] : 0;
        __syncthreads();
        tmp[t] += u;
        __syncthreads();
    }
    if (t < NB) bbase[t] = tmp[t] - v;
    // region sentinels
    if (t == 196) rp[RP_S2 + 100000] = tmp[t] - v;   // end of S2
    if (t == 275) rp[RP_P1 + 20000]  = tmp[t] - v;   // end of P1
    if (t == NB - 1) rp[RP_L1 + 20000] = tmp[t];     // total
}

// ---------------- Phase B: per-bucket counting sort -> final cv + rp ----------------
__global__ __launch_bounds__(256) void bucket_sort_kernel(
    const int* __restrict__ gcursor, const int* __restrict__ bbase,
    const int2* __restrict__ arena, int2* __restrict__ cv, int* __restrict__ rp)
{
    __shared__ int hist[512];
    __shared__ int excl[512];
    __shared__ int wsum[4];

    const int b = blockIdx.x;
    const int t = threadIdx.x;
    const int reg = bucket_region(b);
    const int sh = reg_shift(reg);
    const int stride = 1 << sh;
    const int lb = b - reg_bucketbase(reg);
    const int row_base_local = lb << sh;
    int nrows = reg_rows(reg) - row_base_local;
    if (nrows > stride) nrows = stride;
    const long long slot = reg_arenabase(reg) + (long long)lb * reg_cap(reg);
    const int count = gcursor[b];
    const int fbase = bbase[b];

    for (int i = t; i < 512; i += 256) hist[i] = 0;
    __syncthreads();

    for (int j = t; j < count; j += 256) {
        int key = arena[slot + j].x;
        atomicAdd(&hist[key >> 18], 1);
    }
    __syncthreads();

    // exclusive scan of 512 bins (2 per thread)
    {
        const int lane = t & 63, wave = t >> 6;
        int v0 = hist[t * 2], v1 = hist[t * 2 + 1];
        int s = v0 + v1;
        int inc = s;
        for (int d = 1; d < 64; d <<= 1) {
            int u = __shfl_up(inc, d, 64);
            if (lane >= d) inc += u;
        }
        if (lane == 63) wsum[wave] = inc;
        __syncthreads();
        int woff = 0;
        for (int w = 0; w < wave; ++w) woff += wsum[w];
        int run = woff + inc - s;
        excl[t * 2] = run;
        excl[t * 2 + 1] = run + v0;
    }
    __syncthreads();

    const int grow0 = reg_rpbase(reg) + row_base_local;
    for (int r = t; r < nrows; r += 256)
        rp[grow0 + r] = fbase + excl[r];
    __syncthreads();

    for (int j = t; j < count; j += 256) {
        int2 e = arena[slot + j];
        int r = e.x >> 18;
        int pos = atomicAdd(&excl[r], 1);
        cv[fbase + pos] = make_int2(e.x & 0x3FFFF, e.y);
    }
}

// ---------------- SpMM gather walk: group-of-8, depth-2 software pipeline ----------------
// Lane l: group g = l>>3 handles nnz; sublane s = l&7 loads 16 B of the row.
// Each iteration covers 16 nnz with TWO independent uint4 loads issued
// back-to-back (named regs, no runtime indexing) -> 2 gathers in flight/wave.
// Tail handled by index-clamp (duplicate line loads, vs=0).
__device__ __forceinline__ void walk_row8(
    const int2* __restrict__ cv, int start, int end, int lane,
    const unsigned* __restrict__ xq, const float* __restrict__ xs, float* acc)
{
    const int g  = lane >> 3;
    const int s4 = (lane & 7) * 4;

    for (int sb = start; sb < end; sb += 64) {
        int nn = end - sb; if (nn > 64) nn = 64;
        int2 mycv = make_int2(0, 0);
        float myv = 0.0f;
        if (lane < nn) {
            mycv = cv[sb + lane];
            myv = __int_as_float(mycv.y) * xs[mycv.x];
        }
        const int nn1 = nn - 1;
        for (int jb = 0; jb < nn; jb += 16) {
            int idx0 = jb + g;
            int idx1 = jb + 8 + g;
            int i0 = idx0 < nn1 ? idx0 : nn1;
            int i1 = idx1 < nn1 ? idx1 : nn1;
            int   cs0 = __shfl(mycv.x, i0, 64);
            int   cs1 = __shfl(mycv.x, i1, 64);
            float vs0 = __shfl(myv, i0, 64);
            float vs1 = __shfl(myv, i1, 64);
            vs0 = (idx0 <= nn1) ? vs0 : 0.0f;
            vs1 = (idx1 <= nn1) ? vs1 : 0.0f;
            // issue both loads before any compute
            const uint4 u0 = *reinterpret_cast<const uint4*>(xq + cs0 * 32 + s4);
            const uint4 u1 = *reinterpret_cast<const uint4*>(xq + cs1 * 32 + s4);
#pragma unroll
            for (int w = 0; w < 4; ++w) {
                unsigned uw = (&u0.x)[w];
                acc[w * 4 + 0] = fmaf(vs0, i8f(uw, 0), acc[w * 4 + 0]);
                acc[w * 4 + 1] = fmaf(vs0, i8f(uw, 1), acc[w * 4 + 1]);
                acc[w * 4 + 2] = fmaf(vs0, i8f(uw, 2), acc[w * 4 + 2]);
                acc[w * 4 + 3] = fmaf(vs0, i8f(uw, 3), acc[w * 4 + 3]);
            }
#pragma unroll
            for (int w = 0; w < 4; ++w) {
                unsigned uw = (&u1.x)[w];
                acc[w * 4 + 0] = fmaf(vs1, i8f(uw, 0), acc[w * 4 + 0]);
                acc[w * 4 + 1] = fmaf(vs1, i8f(uw, 1), acc[w * 4 + 1]);
                acc[w * 4 + 2] = fmaf(vs1, i8f(uw, 2), acc[w * 4 + 2]);
                acc[w * 4 + 3] = fmaf(vs1, i8f(uw, 3), acc[w * 4 + 3]);
            }
        }
    }
}

__device__ __forceinline__ void reduce_groups8(float* acc)
{
#pragma unroll
    for (int e = 0; e < 16; ++e) {
        acc[e] += __shfl_xor(acc[e], 8, 64);
        acc[e] += __shfl_xor(acc[e], 16, 64);
        acc[e] += __shfl_xor(acc[e], 32, 64);
    }
}

// stage 1: h1 = p1 @ ego, h2 = l1 @ ego  (int8 gather -> int8 block-scaled rows of xall)
__global__ __launch_bounds__(256) void spmm_stage1_kernel(
    const int* __restrict__ rp, const int2* __restrict__ cv,
    unsigned* __restrict__ xq, float* __restrict__ xs)
{
    int wid = (blockIdx.x * 256 + threadIdx.x) >> 6;
    int lane = threadIdx.x & 63;
    if (wid >= 2 * N_HE) return;
    int rbase, xrow;
    if (wid < N_HE) { rbase = RP_P1 + wid;           xrow = XROW_H1 + wid; }
    else            { rbase = RP_L1 + (wid - N_HE);  xrow = XROW_H2 + (wid - N_HE); }

    float acc[16];
#pragma unroll
    for (int e = 0; e < 16; ++e) acc[e] = 0.0f;
    walk_row8(cv, rp[rbase], rp[rbase + 1], lane, xq, xs, acc);
    reduce_groups8(acc);

    float m = 0.0f;
#pragma unroll
    for (int e = 0; e < 16; ++e) m = fmaxf(m, fabsf(acc[e]));
    m = fmaxf(m, __shfl_xor(m, 1, 64));
    m = fmaxf(m, __shfl_xor(m, 2, 64));
    m = fmaxf(m, __shfl_xor(m, 4, 64));
    float inv = (m > 0.0f) ? 127.0f / m : 0.0f;

    if (lane < 8) {
        uint4 o;
#pragma unroll
        for (int w = 0; w < 4; ++w) {
            int q0 = __float2int_rn(acc[w * 4 + 0] * inv);
            int q1 = __float2int_rn(acc[w * 4 + 1] * inv);
            int q2 = __float2int_rn(acc[w * 4 + 2] * inv);
            int q3 = __float2int_rn(acc[w * 4 + 3] * inv);
            (&o.x)[w] = (q0 & 255) | ((q1 & 255) << 8) | ((q2 & 255) << 16) | ((q3 & 255) << 24);
        }
        *reinterpret_cast<uint4*>(xq + xrow * 32 + lane * 4) = o;
        if (lane == 0) xs[xrow] = m * (1.0f / 127.0f);
    }
}

// stage 2: side = (A|p2|l2) @ xall  — ONE merged walk per output row
__global__ __launch_bounds__(256) void spmm_stage2_kernel(
    const int* __restrict__ rp, const int2* __restrict__ cv,
    const unsigned* __restrict__ xq, const float* __restrict__ xs,
    float* __restrict__ side)
{
    int wid = (blockIdx.x * 256 + threadIdx.x) >> 6;
    int lane = threadIdx.x & 63;
    if (wid >= N_ENT) return;

    float acc[16];
#pragma unroll
    for (int e = 0; e < 16; ++e) acc[e] = 0.0f;
    walk_row8(cv, rp[wid], rp[wid + 1], lane, xq, xs, acc);
    reduce_groups8(acc);

    if (lane < 8) {
        float* yp = side + (long long)wid * DD + lane * 16;
#pragma unroll
        for (int w = 0; w < 4; ++w)
            *reinterpret_cast<float4*>(yp + w * 4) =
                make_float4(acc[w * 4], acc[w * 4 + 1], acc[w * 4 + 2], acc[w * 4 + 3]);
    }
}

// ---------------- MFMA dense epilogue (512 threads, 16 rows/wave) ----------------
union BfFrag { unsigned u[4]; bf16x8 v; };

__global__ __launch_bounds__(512, 4) void dense_mfma_kernel(
    const float* __restrict__ ego, const float* __restrict__ side,
    const float* __restrict__ W1, const float* __restrict__ b1,
    const float* __restrict__ W2, const float* __restrict__ b2,
    float* __restrict__ out)
{
    __shared__ unsigned Wb1[8192];   // 32 KB: W1 bf16, swizzled
    __shared__ unsigned Wb2[8192];   // 32 KB: W2 bf16, swizzled

    const int tid = threadIdx.x;

    for (int idx = tid; idx < 8192; idx += 512) {
        int row = idx >> 6, pc = idx & 63;
        unsigned pk1 = pack_bf16(W1[row * 128 + pc * 2], W1[row * 128 + pc * 2 + 1]);
        unsigned pk2 = pack_bf16(W2[row * 128 + pc * 2], W2[row * 128 + pc * 2 + 1]);
        int boff = row * 256 + ((pc * 4) ^ ((row & 7) << 4));
        *(unsigned*)((char*)Wb1 + boff) = pk1;
        *(unsigned*)((char*)Wb2 + boff) = pk2;
    }
    __syncthreads();

    const int wave = tid >> 6;   // 0..7
    const int lane = tid & 63;
    const int m    = lane & 15;
    const int kg   = lane >> 4;

    float bs[8], bb[8];
#pragma unroll
    for (int c = 0; c < 8; ++c) {
        bs[c] = b1[c * 16 + m];
        bb[c] = b2[c * 16 + m];
    }

    for (int wt = blockIdx.x * 8 + wave; wt < 6250; wt += gridDim.x * 8) {
        const long long r0 = (long long)(wt * 16 + m) * DD;

        f32x4 accS[8], accB[8];
#pragma unroll
        for (int c = 0; c < 8; ++c) { accS[c] = (f32x4)0.0f; accB[c] = (f32x4)0.0f; }

#pragma unroll 1
        for (int kk = 0; kk < 4; ++kk) {
            const int kb = kk * 32 + kg * 8;

            float4 ea = *(const float4*)(ego  + r0 + kb);
            float4 eb = *(const float4*)(ego  + r0 + kb + 4);
            float4 sa = *(const float4*)(side + r0 + kb);
            float4 sb = *(const float4*)(side + r0 + kb + 4);

            BfFrag aS, aB;
            aS.u[0] = pack_bf16(ea.x + sa.x, ea.y + sa.y);
            aS.u[1] = pack_bf16(ea.z + sa.z, ea.w + sa.w);
            aS.u[2] = pack_bf16(eb.x + sb.x, eb.y + sb.y);
            aS.u[3] = pack_bf16(eb.z + sb.z, eb.w + sb.w);
            aB.u[0] = pack_bf16(ea.x * sa.x, ea.y * sa.y);
            aB.u[1] = pack_bf16(ea.z * sa.z, ea.w * sa.w);
            aB.u[2] = pack_bf16(eb.x * sb.x, eb.y * sb.y);
            aB.u[3] = pack_bf16(eb.z * sb.z, eb.w * sb.w);

#pragma unroll
            for (int c = 0; c < 8; ++c) {
                int wrow = c * 16 + m;
                int boff = wrow * 256 + ((kk * 64 + (kg << 4)) ^ ((wrow & 7) << 4));
                bf16x8 w1 = *(const bf16x8*)((const char*)Wb1 + boff);
                bf16x8 w2 = *(const bf16x8*)((const char*)Wb2 + boff);
                accS[c] = __builtin_amdgcn_mfma_f32_16x16x32_bf16(aS.v, w1, accS[c], 0, 0, 0);
                accB[c] = __builtin_amdgcn_mfma_f32_16x16x32_bf16(aB.v, w2, accB[c], 0, 0, 0);
            }
        }

        // D mapping: col = lane&15 (=m), row = kg*4 + q
#pragma unroll
        for (int c = 0; c < 8; ++c) {
#pragma unroll
            for (int q = 0; q < 4; ++q) {
                int orow = wt * 16 + kg * 4 + q;
                out[(long long)orow * DD + c * 16 + m] =
                    lrelu(accS[c][q] + bs[c]) + lrelu(accB[c][q] + bb[c]);
            }
        }
    }
}

extern "C" void kernel_launch(void* const* d_in, const int* in_sizes, int n_in,
                              void* d_out, int out_size, void* d_ws, size_t ws_size,
                              hipStream_t stream)
{
    const float* ego = (const float*)d_in[0];
    const float* W1  = (const float*)d_in[16];
    const float* b1  = (const float*)d_in[17];
    const float* W2  = (const float*)d_in[18];
    const float* b2  = (const float*)d_in[19];

    BuildArgs a;
    a.rows[0] = (const int*)d_in[1];  a.cols[0] = (const int*)d_in[2];  a.vals[0] = (const float*)d_in[3];
    a.rows[1] = (const int*)d_in[4];  a.cols[1] = (const int*)d_in[5];  a.vals[1] = (const float*)d_in[6];
    a.rows[2] = (const int*)d_in[7];  a.cols[2] = (const int*)d_in[8];  a.vals[2] = (const float*)d_in[9];
    a.rows[3] = (const int*)d_in[10]; a.cols[3] = (const int*)d_in[11]; a.vals[3] = (const float*)d_in[12];
    a.rows[4] = (const int*)d_in[13]; a.cols[4] = (const int*)d_in[14]; a.vals[4] = (const float*)d_in[15];
    int nnz[5] = { in_sizes[1], in_sizes[4], in_sizes[7], in_sizes[10], in_sizes[13] };
    a.nnzbase[0] = 0;
    for (int s = 0; s < 5; ++s) a.nnzbase[s + 1] = a.nnzbase[s] + nnz[s];
    const int total = a.nnzbase[5];

    // ---- workspace carve (arena time-shares the side region; arena = 48.8 MB) ----
    char* p = (char*)d_ws;
    float*    side    = (float*)p;
    int2*     arena   = (int2*)p;         p += (size_t)N_ENT * DD * 4;       // 51.2 MB
    unsigned* xq      = (unsigned*)p;     p += (size_t)140032 * 32 * 4;      // 17.9 MB (int8 rows x 140K)
    float*    xs      = (float*)p;        p += (size_t)140032 * 4;           // 560 KB
    int2*     cv      = (int2*)p;         p += (size_t)total * 8;            // 44.8 MB
    int*      rp      = (int*)p;          p += 141056 * 4;
    int*      gcursor = (int*)p;          p += 1024 * 4;
    int*      bbase   = (int*)p;          p += 1024 * 4;

    // build
    hipMemsetAsync(gcursor, 0, NB * sizeof(int), stream);
    quant_ego_kernel<<<(N_ENT * 32 + 255) / 256, 256, 0, stream>>>(ego, xq, xs);
    const int nblk_part = (total + TILE - 1) / TILE;
    partition_kernel<<<nblk_part, 256, 0, stream>>>(a, gcursor, arena);
    bucket_scan_kernel<<<1, 512, 0, stream>>>(gcursor, bbase, rp);
    bucket_sort_kernel<<<NB, 256, 0, stream>>>(gcursor, bbase, arena, cv, rp);

    // spmm (arena region is dead from here; side reuses it)
    spmm_stage1_kernel<<<(2 * N_HE) / 4, 256, 0, stream>>>(rp, cv, xq, xs);
    spmm_stage2_kernel<<<N_ENT / 4, 256, 0, stream>>>(rp, cv, xq, xs, side);

    // dense epilogue (MFMA, 512-thread blocks)
    dense_mfma_kernel<<<782, 512, 0, stream>>>(ego, side, W1, b1, W2, b2, (float*)d_out);
}